// Round 1
// baseline (13517.674 us; speedup 1.0000x reference)
//
#include <hip/hip_runtime.h>

// ---------------- problem constants ----------------
#define Tn   2048
#define Bn   64
#define INn  27
#define H1n  400
#define H2n  200
#define KP   416          // H1 padded to 13 chunks of 32
#define NKC  13           // k-chunks over H1
#define NG   4            // batch groups (16 rows each)
#define BG   16           // batch rows per group
#define MB   25           // blocks per group (16 hidden units each)
#define UPB  16           // hidden units per block

using short8 = __attribute__((ext_vector_type(8))) short;  // 8 bf16 (4 VGPR)
using f32x4  = __attribute__((ext_vector_type(4))) float;  // MFMA acc

// ---------------- workspace layout (bytes) ----------------
// Wcat  bf16 [1600][416]  : 1,331,200
// Wih   bf16 [1600][32]   :   102,400
// Wfc   bf16 [200][416]   :   166,400
// hbuf  bf16 [2][64][416] :   106,496  (ping-pong h_r, bf16)
// bsum  f32  [1600]       :     6,400  (b_ih + b_hh)
// yAcc  f32  [2048*64]    :   524,288
// cnt   u32  [16]         :        64
#define OFF_WCAT 0u
#define OFF_WIH  1331200u
#define OFF_WFC  1433600u
#define OFF_HBUF 1600000u
#define OFF_BSUM 1706496u
#define OFF_YACC 1712896u
#define OFF_CNT  2237184u

__device__ __forceinline__ unsigned short f2bf(float f) {
  unsigned u = __builtin_bit_cast(unsigned, f);
  u += 0x7fffu + ((u >> 16) & 1u);          // round-to-nearest-even
  return (unsigned short)(u >> 16);
}
__device__ __forceinline__ float sigm(float x) {
  float e = __builtin_amdgcn_exp2f(-1.44269504f * x);
  return __builtin_amdgcn_rcpf(1.0f + e);
}
__device__ __forceinline__ float tanh_(float x) {
  float e = __builtin_amdgcn_exp2f(2.88539008f * x);   // exp2(2x*log2e)
  return 1.0f - 2.0f * __builtin_amdgcn_rcpf(e + 1.0f);
}
__device__ __forceinline__ short8 zero8() {
  short8 z;
#pragma unroll
  for (int j = 0; j < 8; ++j) z[j] = 0;
  return z;
}

// ---------------- prep: bf16-pack weights, zero state ----------------
__global__ void prep_kernel(const float* __restrict__ Wih, const float* __restrict__ Whh,
                            const float* __restrict__ bih, const float* __restrict__ bhh,
                            const float* __restrict__ Wfc, unsigned char* __restrict__ ws)
{
  size_t i = (size_t)blockIdx.x * blockDim.x + threadIdx.x;
  const size_t nWcat = (size_t)1600 * KP;   // 665600
  const size_t nWih  = (size_t)1600 * 32;   // 51200
  const size_t nWfc  = (size_t)200 * KP;    // 83200
  const size_t nH    = (size_t)2 * Bn * KP; // 53248
  const size_t nB    = 1600;
  const size_t nY    = (size_t)Tn * Bn;     // 131072
  const size_t nC    = 16;

  if (i < nWcat) {
    unsigned short* p = (unsigned short*)(ws + OFF_WCAT);
    size_t r = i / KP, k = i % KP;
    p[i] = (k < H1n) ? f2bf(Whh[r * H1n + k]) : (unsigned short)0;
    return;
  }
  i -= nWcat;
  if (i < nWih) {
    unsigned short* p = (unsigned short*)(ws + OFF_WIH);
    size_t r = i / 32, k = i % 32;
    p[i] = (k < INn) ? f2bf(Wih[r * INn + k]) : (unsigned short)0;
    return;
  }
  i -= nWih;
  if (i < nWfc) {
    unsigned short* p = (unsigned short*)(ws + OFF_WFC);
    size_t r = i / KP, k = i % KP;
    p[i] = (k < H1n) ? f2bf(Wfc[r * H1n + k]) : (unsigned short)0;
    return;
  }
  i -= nWfc;
  if (i < nH) { ((unsigned short*)(ws + OFF_HBUF))[i] = 0; return; }
  i -= nH;
  if (i < nB) { ((float*)(ws + OFF_BSUM))[i] = bih[i] + bhh[i]; return; }
  i -= nB;
  if (i < nY) { ((float*)(ws + OFF_YACC))[i] = 0.0f; return; }
  i -= nY;
  if (i < nC) { ((unsigned*)(ws + OFF_CNT))[i] = 0u; return; }
}

// ---------------- persistent LSTM kernel ----------------
// grid = NG*MB = 100 blocks x 64 threads (1 wave each); always co-resident.
__global__ void __launch_bounds__(64, 1)
lstm_persist(const float* __restrict__ word, const float* __restrict__ b_fc,
             const float* __restrict__ W_out, unsigned char* __restrict__ ws)
{
  const int lane = threadIdx.x;
  const int lg = lane >> 4;        // k-group 0..3
  const int ln = lane & 15;        // M/N index within tile
  const int bid = blockIdx.x;
  const int g  = bid & (NG - 1);   // batch group
  const int m  = bid >> 2;         // 0..24 : unit-slice within group
  const int b0 = g * BG;
  const int n0 = m * UPB;

  const unsigned short* Wcat = (const unsigned short*)(ws + OFF_WCAT);
  const unsigned short* Wih  = (const unsigned short*)(ws + OFF_WIH);
  const unsigned short* Wfc  = (const unsigned short*)(ws + OFF_WFC);
  unsigned short* hbuf = (unsigned short*)(ws + OFF_HBUF);
  const float* bsum = (const float*)(ws + OFF_BSUM);
  float* yAcc = (float*)(ws + OFF_YACC);
  unsigned* cnt = (unsigned*)(ws + OFF_CNT);

  // ---- persistent weight fragments in VGPRs ----
  // B-frag for gate tile: B[k][n]=W[r0+ln][k]; elem (lg,j) <-> k = kc*32+lg*8+j
  short8 wg[4][NKC + 1];
#pragma unroll
  for (int gg = 0; gg < 4; ++gg) {
    const int r = gg * H1n + n0 + ln;
#pragma unroll
    for (int kc = 0; kc < NKC; ++kc)
      wg[gg][kc] = *(const short8*)(Wcat + (size_t)r * KP + kc * 32 + lg * 8);
    wg[gg][NKC] = *(const short8*)(Wih + (size_t)r * 32 + lg * 8);
  }
  short8 wh[NKC];
  {
    const int j = m * 8 + (ln & 7);  // 8 fc rows per block; ln>=8 lanes zeroed
#pragma unroll
    for (int kc = 0; kc < NKC; ++kc) {
      short8 w = *(const short8*)(Wfc + (size_t)j * KP + kc * 32 + lg * 8);
      wh[kc] = (ln < 8) ? w : zero8();
    }
  }
  float bs[4];
#pragma unroll
  for (int gg = 0; gg < 4; ++gg) bs[gg] = bsum[gg * H1n + n0 + ln];
  const float bfc  = (ln < 8) ? b_fc[m * 8 + ln] : 0.0f;
  const float wout = (ln < 8) ? W_out[m * 8 + ln] : 0.0f;

  float c[4] = {0.f, 0.f, 0.f, 0.f};   // cell state, fp32, lives in regs
  short8 ha[NKC];

  for (int t = 0; t < Tn; ++t) {
    // ---- x fragment (independent of h; overlaps waiting) ----
    short8 xa;
    {
      const float* xrow = word + ((size_t)t * Bn + b0 + ln) * INn;
#pragma unroll
      for (int j = 0; j < 8; ++j) {
        const int k = lg * 8 + j;
        float xv = (k < INn) ? xrow[k] : 0.0f;
        xa[j] = (short)f2bf(xv);
      }
    }

    // ---- wait for h(t-1) from all 25 blocks of this group ----
    if (lane == 0) {
      const unsigned target = (unsigned)(MB * t);
      while (__hip_atomic_load(&cnt[g], __ATOMIC_ACQUIRE, __HIP_MEMORY_SCOPE_AGENT) < target) {}
    }
    __builtin_amdgcn_fence(__ATOMIC_ACQUIRE, "agent");

    // ---- A fragments: h_r(t-1), bf16, direct from global (L2-resident) ----
    const unsigned short* hsrc =
        hbuf + (size_t)((t & 1) ^ 1) * Bn * KP + (size_t)(b0 + ln) * KP;
#pragma unroll
    for (int kc = 0; kc < NKC; ++kc)
      ha[kc] = *(const short8*)(hsrc + kc * 32 + lg * 8);

    // ---- gates = [h|x] @ [Whh|Wih]^T + b  (4 tiles x 14 MFMA) ----
    f32x4 acc[4];
#pragma unroll
    for (int gg = 0; gg < 4; ++gg) {
      f32x4 a; a[0] = bs[gg]; a[1] = bs[gg]; a[2] = bs[gg]; a[3] = bs[gg];
#pragma unroll
      for (int kc = 0; kc < NKC; ++kc)
        a = __builtin_amdgcn_mfma_f32_16x16x32_bf16(ha[kc], wg[gg][kc], a, 0, 0, 0);
      a = __builtin_amdgcn_mfma_f32_16x16x32_bf16(xa, wg[gg][NKC], a, 0, 0, 0);
      acc[gg] = a;
    }

    // ---- per-lane cell update; lane holds (b=lg*4+v, u=ln) for all 4 gates ----
    unsigned short* hdst = hbuf + (size_t)(t & 1) * Bn * KP;
#pragma unroll
    for (int v = 0; v < 4; ++v) {
      const float iv = sigm(acc[0][v]);
      const float fv = sigm(acc[1][v]);
      const float gv = tanh_(acc[2][v]);
      const float ov = sigm(acc[3][v]);
      const float cn = fv * c[v] + iv * gv;
      const float hn = ov * tanh_(cn);
      c[v] = fmaxf(cn, 0.0f);                       // c_r carried
      const float hr = fmaxf(hn, 0.0f);             // h_r carried
      hdst[(size_t)(b0 + lg * 4 + v) * KP + n0 + ln] = f2bf(hr);
    }

    // ---- publish h(t) ----
    __builtin_amdgcn_fence(__ATOMIC_RELEASE, "agent");
    if (lane == 0)
      __hip_atomic_fetch_add(&cnt[g], 1u, __ATOMIC_RELAXED, __HIP_MEMORY_SCOPE_AGENT);

    // ---- MLP head for step t-1 (A-frags = h_r(t-1) already in regs) ----
    if (t > 0) {
      f32x4 ah; ah[0] = 0; ah[1] = 0; ah[2] = 0; ah[3] = 0;
#pragma unroll
      for (int kc = 0; kc < NKC; ++kc)
        ah = __builtin_amdgcn_mfma_f32_16x16x32_bf16(ha[kc], wh[kc], ah, 0, 0, 0);
#pragma unroll
      for (int v = 0; v < 4; ++v) {
        float val = fmaxf(ah[v] + bfc, 0.0f) * wout;   // zero lanes contribute 0
        val += __shfl_xor(val, 1);
        val += __shfl_xor(val, 2);
        val += __shfl_xor(val, 4);
        val += __shfl_xor(val, 8);
        if (ln == 0)
          atomicAdd(&yAcc[(size_t)(t - 1) * Bn + b0 + lg * 4 + v], val);
      }
    }
  }

  // ---- epilogue: head for t = Tn-1 ----
  if (lane == 0) {
    const unsigned target = (unsigned)(MB * Tn);
    while (__hip_atomic_load(&cnt[g], __ATOMIC_ACQUIRE, __HIP_MEMORY_SCOPE_AGENT) < target) {}
  }
  __builtin_amdgcn_fence(__ATOMIC_ACQUIRE, "agent");
  {
    const unsigned short* hsrc =
        hbuf + (size_t)((Tn - 1) & 1) * Bn * KP + (size_t)(b0 + ln) * KP;
#pragma unroll
    for (int kc = 0; kc < NKC; ++kc)
      ha[kc] = *(const short8*)(hsrc + kc * 32 + lg * 8);
    f32x4 ah; ah[0] = 0; ah[1] = 0; ah[2] = 0; ah[3] = 0;
#pragma unroll
    for (int kc = 0; kc < NKC; ++kc)
      ah = __builtin_amdgcn_mfma_f32_16x16x32_bf16(ha[kc], wh[kc], ah, 0, 0, 0);
#pragma unroll
    for (int v = 0; v < 4; ++v) {
      float val = fmaxf(ah[v] + bfc, 0.0f) * wout;
      val += __shfl_xor(val, 1);
      val += __shfl_xor(val, 2);
      val += __shfl_xor(val, 4);
      val += __shfl_xor(val, 8);
      if (ln == 0)
        atomicAdd(&yAcc[(size_t)(Tn - 1) * Bn + b0 + lg * 4 + v], val);
    }
  }
}

// ---------------- finalize: out = sigmoid(z + b_out) ----------------
__global__ void finalize_kernel(const float* __restrict__ yAcc,
                                const float* __restrict__ b_out,
                                float* __restrict__ out)
{
  int i = blockIdx.x * blockDim.x + threadIdx.x;
  if (i < Tn * Bn) out[i] = sigm(yAcc[i] + b_out[0]);
}

extern "C" void kernel_launch(void* const* d_in, const int* in_sizes, int n_in,
                              void* d_out, int out_size, void* d_ws, size_t ws_size,
                              hipStream_t stream)
{
  const float* word  = (const float*)d_in[0];
  const float* W_ih  = (const float*)d_in[1];
  const float* W_hh  = (const float*)d_in[2];
  const float* b_ih  = (const float*)d_in[3];
  const float* b_hh  = (const float*)d_in[4];
  const float* W_fc  = (const float*)d_in[5];
  const float* b_fc  = (const float*)d_in[6];
  const float* W_out = (const float*)d_in[7];
  const float* b_out = (const float*)d_in[8];
  unsigned char* ws  = (unsigned char*)d_ws;

  const int prep_items = 665600 + 51200 + 83200 + 53248 + 1600 + 131072 + 16;
  prep_kernel<<<(prep_items + 255) / 256, 256, 0, stream>>>(W_ih, W_hh, b_ih, b_hh, W_fc, ws);
  lstm_persist<<<NG * MB, 64, 0, stream>>>(word, b_fc, W_out, ws);
  finalize_kernel<<<(Tn * Bn) / 256, 256, 0, stream>>>(
      (const float*)(ws + OFF_YACC), b_out, (float*)d_out);
}

// Round 2
// 11051.297 us; speedup vs baseline: 1.2232x; 1.2232x over previous
//
#include <hip/hip_runtime.h>

// ---------------- problem constants ----------------
#define Tn   2048
#define Bn   64
#define INn  27
#define H1n  400
#define KP   416          // H1 padded to 13 chunks of 32
#define NKC  13           // k-chunks over H1
#define KPQ  104          // KP/4 : u64 quads per h row
#define NG   4            // batch groups (16 rows each)
#define NS   50           // slices (waves) per group, 8 units each
#define NHT  13           // head tiles (200 fc rows -> 13 tiles of 16)

using short8 = __attribute__((ext_vector_type(8))) short;  // 8 bf16 (4 VGPR)
using f32x4  = __attribute__((ext_vector_type(4))) float;  // MFMA acc

// ---------------- workspace layout (bytes, all 16B aligned) ----------------
#define OFF_WBIG 0u          // bf16 [1600][448] reordered [Whh|pad|Wih|pad]   1,433,600
#define OFF_WFC  1433600u    // bf16 [208][416]  zero-padded W_fc               173,056
#define OFF_BSUM 1606656u    // f32  [1600] (b_ih+b_hh, reordered)                6,400
#define OFF_BFC  1613056u    // f32  [208]                                          832
#define OFF_WOUT 1613888u    // f32  [208]                                          832
#define OFF_HBUF 1614720u    // bf16 [2][64][416] ping-pong h_r                 106,496
#define OFF_YACC 1721216u    // f32  [2048*64]                                  524,288
#define OFF_FLAG 2245504u    // u32  [4][64]                                      1,024
#define OFF_XBIG 2246528u    // bf16 [2048][64][32] padded x                  8,388,608
// total 10,635,136 bytes

__device__ __forceinline__ unsigned short f2bf(float f) {
  unsigned u = __builtin_bit_cast(unsigned, f);
  u += 0x7fffu + ((u >> 16) & 1u);          // round-to-nearest-even
  return (unsigned short)(u >> 16);
}
__device__ __forceinline__ float sigm(float x) {
  float e = __builtin_amdgcn_exp2f(-1.44269504f * x);
  return __builtin_amdgcn_rcpf(1.0f + e);
}
__device__ __forceinline__ float tanh_(float x) {
  float e = __builtin_amdgcn_exp2f(2.88539008f * x);   // exp2(2x*log2e)
  return 1.0f - 2.0f * __builtin_amdgcn_rcpf(e + 1.0f);
}
struct U128 { unsigned long long lo, hi; };

// row' -> original gate row. Wave slice s owns units u0=8s..8s+7 as 2 tiles:
// tile0 cols: gate i (c<8) / f (c>=8) of unit u0+(c&7); tile1: g / o.
__device__ __forceinline__ int gate_row(int rowp) {
  int s    = rowp >> 5;
  int r32  = rowp & 31;
  int tile = r32 >> 4;
  int c    = r32 & 15;
  int gate = tile * 2 + (c >> 3);
  int u    = s * 8 + (c & 7);
  return gate * H1n + u;
}

// ---------------- prep: pack/reorder weights, convert x, zero state ----------------
__global__ void prep_kernel(const float* __restrict__ word,
                            const float* __restrict__ Wih, const float* __restrict__ Whh,
                            const float* __restrict__ bih, const float* __restrict__ bhh,
                            const float* __restrict__ Wfc, const float* __restrict__ bfc,
                            const float* __restrict__ Wout,
                            unsigned char* __restrict__ ws)
{
  size_t i = (size_t)blockIdx.x * blockDim.x + threadIdx.x;
  const size_t nWbig = (size_t)1600 * 448;   // 716800
  const size_t nWfc  = (size_t)208 * KP;     // 86528
  const size_t nBs   = 1600;
  const size_t nBfc  = 208;
  const size_t nWo   = 208;
  const size_t nH    = (size_t)2 * Bn * KP;  // 53248
  const size_t nY    = (size_t)Tn * Bn;      // 131072
  const size_t nF    = 256;
  const size_t nX    = (size_t)Tn * Bn * 32; // 4194304

  if (i < nWbig) {
    unsigned short* p = (unsigned short*)(ws + OFF_WBIG);
    int rowp = (int)(i / 448), k = (int)(i % 448);
    int r = gate_row(rowp);
    float v = 0.0f;
    if (k < H1n)            v = Whh[(size_t)r * H1n + k];
    else if (k >= 416) { int j = k - 416; if (j < INn) v = Wih[(size_t)r * INn + j]; }
    p[i] = f2bf(v);
    return;
  }
  i -= nWbig;
  if (i < nWfc) {
    unsigned short* p = (unsigned short*)(ws + OFF_WFC);
    int r = (int)(i / KP), k = (int)(i % KP);
    p[i] = (r < 200 && k < H1n) ? f2bf(Wfc[(size_t)r * H1n + k]) : (unsigned short)0;
    return;
  }
  i -= nWfc;
  if (i < nBs) { ((float*)(ws + OFF_BSUM))[i] = bih[gate_row((int)i)] + bhh[gate_row((int)i)]; return; }
  i -= nBs;
  if (i < nBfc) { ((float*)(ws + OFF_BFC))[i] = (i < 200) ? bfc[i] : 0.0f; return; }
  i -= nBfc;
  if (i < nWo) { ((float*)(ws + OFF_WOUT))[i] = (i < 200) ? Wout[i] : 0.0f; return; }
  i -= nWo;
  if (i < nH) { ((unsigned short*)(ws + OFF_HBUF))[i] = 0; return; }
  i -= nH;
  if (i < nY) { ((float*)(ws + OFF_YACC))[i] = 0.0f; return; }
  i -= nY;
  if (i < nF) { ((unsigned*)(ws + OFF_FLAG))[i] = 0u; return; }
  i -= nF;
  if (i < nX) {
    unsigned short* p = (unsigned short*)(ws + OFF_XBIG);
    size_t tb = i >> 5; int k = (int)(i & 31);
    p[i] = (k < INn) ? f2bf(word[tb * INn + k]) : (unsigned short)0;
    return;
  }
}

// ---------------- persistent LSTM kernel ----------------
// grid = 50 blocks x 256 threads. Wave w of block b: group g=w, slice s=b.
// Fence-free: all cross-block traffic via relaxed AGENT-scope atomics (sc0/sc1).
__global__ void __launch_bounds__(256, 1)
lstm_persist(unsigned char* __restrict__ ws)
{
  const int l  = threadIdx.x & 63;
  const int g  = threadIdx.x >> 6;   // batch group 0..3
  const int s  = blockIdx.x;         // unit slice 0..49
  const int lg = l >> 4, ln = l & 15;
  const int b0 = g * 16;

  const unsigned short* Wbig = (const unsigned short*)(ws + OFF_WBIG);
  const unsigned short* Wfc2 = (const unsigned short*)(ws + OFF_WFC);
  const unsigned short* Xbig = (const unsigned short*)(ws + OFF_XBIG);
  const float* bsum = (const float*)(ws + OFF_BSUM);
  const float* bfc2 = (const float*)(ws + OFF_BFC);
  const float* wout2 = (const float*)(ws + OFF_WOUT);
  unsigned long long* hbufq = (unsigned long long*)(ws + OFF_HBUF);
  float* yAcc = (float*)(ws + OFF_YACC);
  unsigned* flags = (unsigned*)(ws + OFF_FLAG);

  // ---- persistent weight fragments (VGPR) ----
  short8 wv[2][14];
#pragma unroll
  for (int tile = 0; tile < 2; ++tile) {
    const int rowp = s * 32 + tile * 16 + ln;
#pragma unroll
    for (int kc = 0; kc < 14; ++kc)
      wv[tile][kc] = *(const short8*)(Wbig + (size_t)rowp * 448 + kc * 32 + lg * 8);
  }
  float bs0 = bsum[s * 32 + ln];
  float bs1 = bsum[s * 32 + 16 + ln];

  const bool isHead = (s < NHT);
  short8 whv[13];
  float bfcv = 0.f, woutv = 0.f;
  if (isHead) {
    const int r = s * 16 + ln;
#pragma unroll
    for (int kc = 0; kc < 13; ++kc)
      whv[kc] = *(const short8*)(Wfc2 + (size_t)r * KP + kc * 32 + lg * 8);
    bfcv  = bfc2[r];
    woutv = wout2[r];
  }

  __shared__ __align__(8) unsigned short sm[4][8][20];   // [wave][u][b+pad]

  float c[4] = {0.f, 0.f, 0.f, 0.f};

  for (int t = 0; t < Tn; ++t) {
    // ---- x fragment (plain load, L2-warm) ----
    short8 xa = *(const short8*)(Xbig + ((size_t)t * Bn + b0 + ln) * 32 + lg * 8);

    // ---- wait for h(t-1): poll per-producer flag words (no RMW) ----
    if (t > 0) {
      const unsigned* fl = flags + (g << 6);
      while (true) {
        unsigned f = 0xFFFFFFFFu;
        if (l < NS) f = __hip_atomic_load(&fl[l], __ATOMIC_RELAXED, __HIP_MEMORY_SCOPE_AGENT);
        if (__all((int)(f >= (unsigned)t))) break;
      }
    }
    asm volatile("" ::: "memory");

    // ---- A fragments: h_r(t-1) via coherent u64 loads (bypass L1/L2) ----
    const unsigned long long* hsq =
        hbufq + (size_t)((t & 1) ^ 1) * (Bn * KPQ) + (size_t)(b0 + ln) * KPQ;
    short8 ha[13];
#pragma unroll
    for (int kc = 0; kc < 13; ++kc) {
      U128 u;
      u.lo = __hip_atomic_load(hsq + kc * 8 + lg * 2,     __ATOMIC_RELAXED, __HIP_MEMORY_SCOPE_AGENT);
      u.hi = __hip_atomic_load(hsq + kc * 8 + lg * 2 + 1, __ATOMIC_RELAXED, __HIP_MEMORY_SCOPE_AGENT);
      ha[kc] = __builtin_bit_cast(short8, u);
    }

    // ---- gates (2 tiles x 14 MFMA) ----
    f32x4 a0 = {bs0, bs0, bs0, bs0};
    f32x4 a1 = {bs1, bs1, bs1, bs1};
#pragma unroll
    for (int kc = 0; kc < 13; ++kc) {
      a0 = __builtin_amdgcn_mfma_f32_16x16x32_bf16(ha[kc], wv[0][kc], a0, 0, 0, 0);
      a1 = __builtin_amdgcn_mfma_f32_16x16x32_bf16(ha[kc], wv[1][kc], a1, 0, 0, 0);
    }
    a0 = __builtin_amdgcn_mfma_f32_16x16x32_bf16(xa, wv[0][13], a0, 0, 0, 0);
    a1 = __builtin_amdgcn_mfma_f32_16x16x32_bf16(xa, wv[1][13], a1, 0, 0, 0);

    // ---- head MFMA for y(t-1) (XDL pipe; overlaps cell-update VALU) ----
    f32x4 hy = {0.f, 0.f, 0.f, 0.f};
    if (isHead && t > 0) {
#pragma unroll
      for (int kc = 0; kc < 13; ++kc)
        hy = __builtin_amdgcn_mfma_f32_16x16x32_bf16(ha[kc], whv[kc], hy, 0, 0, 0);
    }

    // ---- cell update: lanes l and l^8 both own unit u0+(ln&7), b=4lg+v ----
    float hr[4];
    const bool hiHalf = (l & 8) != 0;
#pragma unroll
    for (int v = 0; v < 4; ++v) {
      float o0 = a0[v], o1 = a1[v];
      float p0 = __shfl_xor(o0, 8);
      float p1 = __shfl_xor(o1, 8);
      float iv = hiHalf ? p0 : o0;
      float fv = hiHalf ? o0 : p0;
      float gv = hiHalf ? p1 : o1;
      float ov = hiHalf ? o1 : p1;
      iv = sigm(iv); fv = sigm(fv); gv = tanh_(gv); ov = sigm(ov);
      float cn = fv * c[v] + iv * gv;
      float hn = ov * tanh_(cn);
      c[v]  = fmaxf(cn, 0.f);
      hr[v] = fmaxf(hn, 0.f);
    }

    // ---- transpose 8u x 16b via LDS (wave-local, no barrier) ----
    if (!hiHalf) {  // lanes ln<8 hold canonical copy
      unsigned p01 = (unsigned)f2bf(hr[0]) | ((unsigned)f2bf(hr[1]) << 16);
      unsigned p23 = (unsigned)f2bf(hr[2]) | ((unsigned)f2bf(hr[3]) << 16);
      unsigned* pr = (unsigned*)&sm[g][ln][lg << 2];
      pr[0] = p01;
      pr[1] = p23;
    }
    // ---- publish h(t): coherent u64 stores, [b][u] layout ----
    unsigned long long* hdq = hbufq + (size_t)(t & 1) * (Bn * KPQ);
    if (l < 32) {
      const int b = l & 15, q = l >> 4;
      unsigned long long hq =  (unsigned long long)sm[g][4 * q + 0][b]
          | ((unsigned long long)sm[g][4 * q + 1][b] << 16)
          | ((unsigned long long)sm[g][4 * q + 2][b] << 32)
          | ((unsigned long long)sm[g][4 * q + 3][b] << 48);
      __hip_atomic_store(hdq + (size_t)(b0 + b) * KPQ + 2 * s + q, hq,
                         __ATOMIC_RELAXED, __HIP_MEMORY_SCOPE_AGENT);
    }

    // ---- release: drain stores, then set flag ----
    asm volatile("s_waitcnt vmcnt(0)" ::: "memory");
    if (l == 0)
      __hip_atomic_store(&flags[(g << 6) + s], (unsigned)(t + 1),
                         __ATOMIC_RELAXED, __HIP_MEMORY_SCOPE_AGENT);

    // ---- head finish for y(t-1) (off critical path) ----
    if (isHead && t > 0) {
#pragma unroll
      for (int v = 0; v < 4; ++v) {
        float val = fmaxf(hy[v] + bfcv, 0.f) * woutv;
        val += __shfl_xor(val, 1);
        val += __shfl_xor(val, 2);
        val += __shfl_xor(val, 4);
        val += __shfl_xor(val, 8);
        if (ln == 0)
          atomicAdd(&yAcc[(size_t)(t - 1) * Bn + b0 + (lg << 2) + v], val);
      }
    }
  }

  // ---- epilogue: y(Tn-1) ----
  if (isHead) {
    const unsigned* fl = flags + (g << 6);
    while (true) {
      unsigned f = 0xFFFFFFFFu;
      if (l < NS) f = __hip_atomic_load(&fl[l], __ATOMIC_RELAXED, __HIP_MEMORY_SCOPE_AGENT);
      if (__all((int)(f >= (unsigned)Tn))) break;
    }
    asm volatile("" ::: "memory");
    const unsigned long long* hsq = hbufq + (size_t)((Tn - 1) & 1) * (Bn * KPQ) + (size_t)(b0 + ln) * KPQ;
    f32x4 hy = {0.f, 0.f, 0.f, 0.f};
#pragma unroll
    for (int kc = 0; kc < 13; ++kc) {
      U128 u;
      u.lo = __hip_atomic_load(hsq + kc * 8 + lg * 2,     __ATOMIC_RELAXED, __HIP_MEMORY_SCOPE_AGENT);
      u.hi = __hip_atomic_load(hsq + kc * 8 + lg * 2 + 1, __ATOMIC_RELAXED, __HIP_MEMORY_SCOPE_AGENT);
      short8 hafin = __builtin_bit_cast(short8, u);
      hy = __builtin_amdgcn_mfma_f32_16x16x32_bf16(hafin, whv[kc], hy, 0, 0, 0);
    }
#pragma unroll
    for (int v = 0; v < 4; ++v) {
      float val = fmaxf(hy[v] + bfcv, 0.f) * woutv;
      val += __shfl_xor(val, 1);
      val += __shfl_xor(val, 2);
      val += __shfl_xor(val, 4);
      val += __shfl_xor(val, 8);
      if (ln == 0)
        atomicAdd(&yAcc[(size_t)(Tn - 1) * Bn + b0 + (lg << 2) + v], val);
    }
  }
}

// ---------------- finalize: out = sigmoid(z + b_out) ----------------
__global__ void finalize_kernel(const float* __restrict__ yAcc,
                                const float* __restrict__ b_out,
                                float* __restrict__ out)
{
  int i = blockIdx.x * blockDim.x + threadIdx.x;
  if (i < Tn * Bn) out[i] = sigm(yAcc[i] + b_out[0]);
}

extern "C" void kernel_launch(void* const* d_in, const int* in_sizes, int n_in,
                              void* d_out, int out_size, void* d_ws, size_t ws_size,
                              hipStream_t stream)
{
  const float* word  = (const float*)d_in[0];
  const float* W_ih  = (const float*)d_in[1];
  const float* W_hh  = (const float*)d_in[2];
  const float* b_ih  = (const float*)d_in[3];
  const float* b_hh  = (const float*)d_in[4];
  const float* W_fc  = (const float*)d_in[5];
  const float* b_fc  = (const float*)d_in[6];
  const float* W_out = (const float*)d_in[7];
  const float* b_out = (const float*)d_in[8];
  unsigned char* ws  = (unsigned char*)d_ws;

  const long long prep_items = 716800LL + 86528 + 1600 + 208 + 208 + 53248 + 131072 + 256 + 4194304;
  const int prep_blocks = (int)((prep_items + 255) / 256);
  prep_kernel<<<prep_blocks, 256, 0, stream>>>(word, W_ih, W_hh, b_ih, b_hh, W_fc, b_fc, W_out, ws);
  lstm_persist<<<NS, 256, 0, stream>>>(ws);
  finalize_kernel<<<(Tn * Bn + 255) / 256, 256, 0, stream>>>(
      (const float*)(ws + OFF_YACC), b_out, (float*)d_out);
}

// Round 4
// 10497.083 us; speedup vs baseline: 1.2878x; 1.0528x over previous
//
#include <hip/hip_runtime.h>

// ---------------- problem constants ----------------
#define Tn   2048
#define Bn   64
#define INn  27
#define H1n  400
#define KP   416          // H1 padded to 13 chunks of 32
#define NS   50           // producer slices (blocks), 8 units each
#define NHT  13           // head tiles (200 fc rows -> 13 tiles of 16)

using short8 = __attribute__((ext_vector_type(8))) short;  // 8 bf16 (4 VGPR)
using f32x4  = __attribute__((ext_vector_type(4))) float;  // MFMA acc

// ---------------- workspace layout (bytes) ----------------
#define OFF_WBIG  0u         // bf16 [1600][448]  [Whh|pad|Wih]      1,433,600
#define OFF_WFC   1433600u   // bf16 [208][416]                        173,056
#define OFF_BSUM  1606656u   // f32  [1600]                              6,400
#define OFF_BFC   1613056u   // f32  [208]                                 832
#define OFF_WOUT  1613888u   // f32  [208]                                 832
#define OFF_HBUF  1614720u   // bf16 [2][64][416] ping-pong h_r        106,496
#define OFF_FLAG  1721216u   // u32  [4][64]                             1,024
#define OFF_YPART 1722240u   // f32  [13][2048*64] head partials     6,815,744
// total 8,537,984

__device__ __forceinline__ unsigned short f2bf(float f) {
  unsigned u = __builtin_bit_cast(unsigned, f);
  u += 0x7fffu + ((u >> 16) & 1u);          // round-to-nearest-even
  return (unsigned short)(u >> 16);
}
__device__ __forceinline__ float sigm(float x) {
  float e = __builtin_amdgcn_exp2f(-1.44269504f * x);
  return __builtin_amdgcn_rcpf(1.0f + e);
}
__device__ __forceinline__ float tanh_(float x) {
  float e = __builtin_amdgcn_exp2f(2.88539008f * x);
  return 1.0f - 2.0f * __builtin_amdgcn_rcpf(e + 1.0f);
}

// ---- agent-coherent (sc0 sc1: full L1/L2 bypass, L3 coherence point) ops ----
__device__ __forceinline__ unsigned ld_flag(const unsigned* p) {
  unsigned v;
  asm volatile("global_load_dword %0, %1, off sc0 sc1\n\ts_waitcnt vmcnt(0)"
               : "=v"(v) : "v"(p) : "memory");
  return v;
}
__device__ __forceinline__ short8 ld_h16(const void* p) {
  short8 v;
  asm volatile("global_load_dwordx4 %0, %1, off sc0 sc1" : "=v"(v) : "v"(p) : "memory");
  return v;
}
__device__ __forceinline__ void st_h8(void* p, unsigned long long v) {
  asm volatile("global_store_dwordx2 %0, %1, off sc0 sc1" :: "v"(p), "v"(v) : "memory");
}
__device__ __forceinline__ void st_flag(void* p, unsigned v) {
  asm volatile("global_store_dword %0, %1, off sc0 sc1" :: "v"(p), "v"(v) : "memory");
}

// rowp (0..1599) -> original gate row. Slice s owns units 8s..8s+7 as
// 2 tiles: tile0 = gates i|f, tile1 = g|o (i/f split at col bit 3).
__device__ __forceinline__ int gate_row(int rowp) {
  int s    = rowp >> 5;
  int r32  = rowp & 31;
  int tile = r32 >> 4;
  int c    = r32 & 15;
  int gate = tile * 2 + (c >> 3);
  int u    = s * 8 + (c & 7);
  return gate * H1n + u;
}

// ---------------- prep ----------------
__global__ void prep_kernel(const float* __restrict__ Wih, const float* __restrict__ Whh,
                            const float* __restrict__ bih, const float* __restrict__ bhh,
                            const float* __restrict__ Wfc, const float* __restrict__ bfc,
                            const float* __restrict__ Wout,
                            unsigned char* __restrict__ ws)
{
  size_t i = (size_t)blockIdx.x * blockDim.x + threadIdx.x;
  const size_t n1 = (size_t)1600 * 448;   // Wbig        716800
  const size_t n2 = (size_t)208 * KP;     // Wfc          86528
  const size_t n3 = 1600;                 // bsum
  const size_t n4 = 208;                  // bfc
  const size_t n5 = 208;                  // wout
  const size_t n6 = (size_t)2 * Bn * KP;  // hbuf         53248
  const size_t n7 = 256;                  // flags

  if (i < n1) {
    unsigned short* p = (unsigned short*)(ws + OFF_WBIG);
    int rowp = (int)(i / 448), k = (int)(i % 448);
    int r = gate_row(rowp);
    float v = 0.0f;
    if (k < H1n)            v = Whh[(size_t)r * H1n + k];
    else if (k >= 416) { int j = k - 416; if (j < INn) v = Wih[(size_t)r * INn + j]; }
    p[i] = f2bf(v);
    return;
  }
  i -= n1;
  if (i < n2) {
    unsigned short* p = (unsigned short*)(ws + OFF_WFC);
    int r = (int)(i / KP), k = (int)(i % KP);
    p[i] = (r < 200 && k < H1n) ? f2bf(Wfc[(size_t)r * H1n + k]) : (unsigned short)0;
    return;
  }
  i -= n2;
  if (i < n3) { int r = gate_row((int)i);
    ((float*)(ws + OFF_BSUM))[i] = bih[r] + bhh[r]; return; }
  i -= n3;
  if (i < n4) { ((float*)(ws + OFF_BFC))[i] = (i < 200) ? bfc[i] : 0.0f; return; }
  i -= n4;
  if (i < n5) { ((float*)(ws + OFF_WOUT))[i] = (i < 200) ? Wout[i] : 0.0f; return; }
  i -= n5;
  if (i < n6) { ((unsigned short*)(ws + OFF_HBUF))[i] = 0; return; }
  i -= n6;
  if (i < n7) { ((unsigned*)(ws + OFF_FLAG))[i] = 0u; return; }
}

// ---------------- persistent LSTM ----------------
// 50 blocks x 256 thr. Wave w = batch group g (16 rows); block = slice s
// (8 hidden units, 2 gate tiles). All cross-block traffic via sc0sc1 ops at
// the L3 coherence point; per-producer flags, batched loads, one waitcnt.
__global__ void __launch_bounds__(256, 1)
lstm_persist(const float* __restrict__ word, unsigned char* __restrict__ ws)
{
  const int l  = threadIdx.x & 63;
  const int g  = threadIdx.x >> 6;   // batch group 0..3
  const int s  = blockIdx.x;         // slice 0..49
  const int lg = l >> 4, ln = l & 15;
  const int b0 = g * 16;

  const unsigned short* Wbig = (const unsigned short*)(ws + OFF_WBIG);
  const unsigned short* Wfc2 = (const unsigned short*)(ws + OFF_WFC);
  const float* bsum  = (const float*)(ws + OFF_BSUM);
  const float* bfc2  = (const float*)(ws + OFF_BFC);
  const float* wout2 = (const float*)(ws + OFF_WOUT);
  char* hbase = (char*)(ws + OFF_HBUF);
  float* yPart = (float*)(ws + OFF_YPART);
  unsigned* flags = (unsigned*)(ws + OFF_FLAG);

  // ---- persistent weight fragments (VGPR/AGPR, unified file) ----
  short8 wv[2][14];
#pragma unroll
  for (int tile = 0; tile < 2; ++tile) {
    const int rowp = s * 32 + tile * 16 + ln;
#pragma unroll
    for (int kc = 0; kc < 14; ++kc)
      wv[tile][kc] = *(const short8*)(Wbig + (size_t)rowp * 448 + kc * 32 + lg * 8);
  }
  const float bs0 = bsum[s * 32 + ln];
  const float bs1 = bsum[s * 32 + 16 + ln];

  const bool isHead = (s < NHT);
  short8 whv[13];
  float bfcv = 0.f, woutv = 0.f;
  if (isHead) {
    const int r = s * 16 + ln;
#pragma unroll
    for (int kc = 0; kc < 13; ++kc)
      whv[kc] = *(const short8*)(Wfc2 + (size_t)r * KP + kc * 32 + lg * 8);
    bfcv  = bfc2[r];
    woutv = wout2[r];
  }

  __shared__ __align__(8) unsigned short sm[4][8][20];   // [wave][u][b+pad]
  float c[4] = {0.f, 0.f, 0.f, 0.f};
  short8 ha[13];

  for (int t = 0; t < Tn; ++t) {
    // ---- x fragment: direct f32 loads + cvt (independent of h) ----
    short8 xa;
    {
      const float* xrow = word + ((size_t)t * Bn + b0 + ln) * INn;
#pragma unroll
      for (int j = 0; j < 8; ++j) {
        const int k = lg * 8 + j;
        xa[j] = (short)f2bf((k < INn) ? xrow[k] : 0.0f);
      }
    }

    // ---- wait for h(t-1): one 50-lane gather per poll iteration ----
    if (t > 0) {
      const unsigned* fl = flags + (g << 6);
      const unsigned tt = (unsigned)t;
      while (true) {
        unsigned fv = 0xFFFFFFFFu;
        if (l < NS) fv = ld_flag(&fl[l]);
        if (__all(fv >= tt)) break;
        __builtin_amdgcn_s_sleep(1);
      }
    }

    // ---- A fragments: 13 pipelined coherent b128 loads, ONE waitcnt ----
    const char* hsrc = hbase
        + ((size_t)((t & 1) ^ 1) * Bn * KP + (size_t)(b0 + ln) * KP) * 2 + lg * 16;
#pragma unroll
    for (int kc = 0; kc < 13; ++kc)
      ha[kc] = ld_h16(hsrc + kc * 64);
    asm volatile("s_waitcnt vmcnt(0)" ::: "memory");
    __builtin_amdgcn_sched_barrier(0);

    // ---- gates (2 tiles x 14 MFMA) ----
    f32x4 a0 = {bs0, bs0, bs0, bs0};
    f32x4 a1 = {bs1, bs1, bs1, bs1};
#pragma unroll
    for (int kc = 0; kc < 13; ++kc) {
      a0 = __builtin_amdgcn_mfma_f32_16x16x32_bf16(ha[kc], wv[0][kc], a0, 0, 0, 0);
      a1 = __builtin_amdgcn_mfma_f32_16x16x32_bf16(ha[kc], wv[1][kc], a1, 0, 0, 0);
    }
    a0 = __builtin_amdgcn_mfma_f32_16x16x32_bf16(xa, wv[0][13], a0, 0, 0, 0);
    a1 = __builtin_amdgcn_mfma_f32_16x16x32_bf16(xa, wv[1][13], a1, 0, 0, 0);

    // ---- cell update; lanes l and l^8 share unit, hold i/f and g/o ----
    float hr[4];
    const bool hiHalf = (l & 8) != 0;
#pragma unroll
    for (int v = 0; v < 4; ++v) {
      float o0 = a0[v], o1 = a1[v];
      float p0 = __shfl_xor(o0, 8);
      float p1 = __shfl_xor(o1, 8);
      float iv = hiHalf ? p0 : o0;
      float fv = hiHalf ? o0 : p0;
      float gv = hiHalf ? p1 : o1;
      float ov = hiHalf ? o1 : p1;
      iv = sigm(iv); fv = sigm(fv); gv = tanh_(gv); ov = sigm(ov);
      float cn = fv * c[v] + iv * gv;
      float hn = ov * tanh_(cn);
      c[v]  = fmaxf(cn, 0.f);
      hr[v] = fmaxf(hn, 0.f);
    }

    // ---- transpose 8u x 16b via wave-local LDS (in-wave, compiler-waited) ----
    if (!hiHalf) {
      unsigned p01 = (unsigned)f2bf(hr[0]) | ((unsigned)f2bf(hr[1]) << 16);
      unsigned p23 = (unsigned)f2bf(hr[2]) | ((unsigned)f2bf(hr[3]) << 16);
      unsigned* pr = (unsigned*)&sm[g][ln][lg << 2];
      pr[0] = p01;
      pr[1] = p23;
    }
    // ---- publish h(t): 32-lane u64 coherent stores ----
    char* hdst = hbase + (size_t)(t & 1) * Bn * KP * 2;
    if (l < 32) {
      const int b = l & 15, q = l >> 4;
      unsigned long long hq =  (unsigned long long)sm[g][4 * q + 0][b]
          | ((unsigned long long)sm[g][4 * q + 1][b] << 16)
          | ((unsigned long long)sm[g][4 * q + 2][b] << 32)
          | ((unsigned long long)sm[g][4 * q + 3][b] << 48);
      st_h8(hdst + (size_t)(b0 + b) * KP * 2 + s * 16 + q * 8, hq);
    }
    // ---- release: one drain, then flag (fire-and-forget) ----
    asm volatile("s_waitcnt vmcnt(0)" ::: "memory");
    if (l == 0)
      st_flag(&flags[(g << 6) + s], (unsigned)(t + 1));

    // ---- head tile s for y(t-1): off critical path ----
    if (isHead && t > 0) {
      f32x4 hy = {0.f, 0.f, 0.f, 0.f};
#pragma unroll
      for (int kc = 0; kc < 13; ++kc)
        hy = __builtin_amdgcn_mfma_f32_16x16x32_bf16(ha[kc], whv[kc], hy, 0, 0, 0);
#pragma unroll
      for (int v = 0; v < 4; ++v) {
        float val = fmaxf(hy[v] + bfcv, 0.f) * woutv;
        val += __shfl_xor(val, 1);
        val += __shfl_xor(val, 2);
        val += __shfl_xor(val, 4);
        val += __shfl_xor(val, 8);
        if (ln == 0)
          yPart[(size_t)s * Tn * Bn + (size_t)(t - 1) * Bn + b0 + (lg << 2) + v] = val;
      }
    }
  }

  // ---- epilogue: y(Tn-1) ----
  if (isHead) {
    const unsigned* fl = flags + (g << 6);
    while (true) {
      unsigned fv = 0xFFFFFFFFu;
      if (l < NS) fv = ld_flag(&fl[l]);
      if (__all(fv >= (unsigned)Tn)) break;
      __builtin_amdgcn_s_sleep(1);
    }
    const char* hsrc = hbase
        + ((size_t)((Tn - 1) & 1) * Bn * KP + (size_t)(b0 + ln) * KP) * 2 + lg * 16;
#pragma unroll
    for (int kc = 0; kc < 13; ++kc)
      ha[kc] = ld_h16(hsrc + kc * 64);
    asm volatile("s_waitcnt vmcnt(0)" ::: "memory");
    __builtin_amdgcn_sched_barrier(0);
    f32x4 hy = {0.f, 0.f, 0.f, 0.f};
#pragma unroll
    for (int kc = 0; kc < 13; ++kc)
      hy = __builtin_amdgcn_mfma_f32_16x16x32_bf16(ha[kc], whv[kc], hy, 0, 0, 0);
#pragma unroll
    for (int v = 0; v < 4; ++v) {
      float val = fmaxf(hy[v] + bfcv, 0.f) * woutv;
      val += __shfl_xor(val, 1);
      val += __shfl_xor(val, 2);
      val += __shfl_xor(val, 4);
      val += __shfl_xor(val, 8);
      if (ln == 0)
        yPart[(size_t)s * Tn * Bn + (size_t)(Tn - 1) * Bn + b0 + (lg << 2) + v] = val;
    }
  }
}

// ---------------- finalize: out = sigmoid(sum of 13 partials + b_out) ----------------
__global__ void finalize_kernel(const float* __restrict__ yPart,
                                const float* __restrict__ b_out,
                                float* __restrict__ out)
{
  int i = blockIdx.x * blockDim.x + threadIdx.x;
  if (i < Tn * Bn) {
    float sum = b_out[0];
#pragma unroll
    for (int p = 0; p < 13; ++p)
      sum += yPart[(size_t)p * Tn * Bn + i];
    out[i] = sigm(sum);
  }
}

extern "C" void kernel_launch(void* const* d_in, const int* in_sizes, int n_in,
                              void* d_out, int out_size, void* d_ws, size_t ws_size,
                              hipStream_t stream)
{
  const float* word  = (const float*)d_in[0];
  const float* W_ih  = (const float*)d_in[1];
  const float* W_hh  = (const float*)d_in[2];
  const float* b_ih  = (const float*)d_in[3];
  const float* b_hh  = (const float*)d_in[4];
  const float* W_fc  = (const float*)d_in[5];
  const float* b_fc  = (const float*)d_in[6];
  const float* W_out = (const float*)d_in[7];
  const float* b_out = (const float*)d_in[8];
  unsigned char* ws  = (unsigned char*)d_ws;

  const long long prep_items = 716800LL + 86528 + 1600 + 208 + 208 + 53248 + 256;
  prep_kernel<<<(int)((prep_items + 255) / 256), 256, 0, stream>>>(
      W_ih, W_hh, b_ih, b_hh, W_fc, b_fc, W_out, ws);
  lstm_persist<<<NS, 256, 0, stream>>>(word, ws);
  finalize_kernel<<<(Tn * Bn + 255) / 256, 256, 0, stream>>>(
      (const float*)(ws + OFF_YPART), b_out, (float*)d_out);
}

// Round 5
// 7917.459 us; speedup vs baseline: 1.7073x; 1.3258x over previous
//
#include <hip/hip_runtime.h>

// ---------------- problem constants ----------------
#define Tn   2048
#define Bn   64
#define INn  27
#define H1n  400
#define KP   416          // H1 padded to 13 chunks of 32
#define NSL  25           // producer blocks (slices), 16 units each
#define NHT  13           // head tiles (200 fc rows -> 13 tiles of 16)

using short8 = __attribute__((ext_vector_type(8))) short;  // 8 bf16 (4 VGPR)
using f32x4  = __attribute__((ext_vector_type(4))) float;  // MFMA acc

// ---------------- workspace layout (bytes) ----------------
#define OFF_WBIG  0u         // bf16 [1600][448]  [Whh|pad|Wih]      1,433,600
#define OFF_WFC   1433600u   // bf16 [208][416]                        173,056
#define OFF_BSUM  1606656u   // f32  [1600]                              6,400
#define OFF_BFC   1613056u   // f32  [208]                                 832
#define OFF_WOUT  1613888u   // f32  [208]                                 832
#define OFF_HBUF  1614720u   // bf16 [2][64][416] ping-pong h_r        106,496
#define OFF_FLAG  1721216u   // u32  [25 cons][4 grp][32] mailboxes      12,800
#define OFF_YPART 1734016u   // f32  [13][2048*64] head partials      6,815,744
// total 8,549,760

__device__ __forceinline__ unsigned short f2bf(float f) {
  unsigned u = __builtin_bit_cast(unsigned, f);
  u += 0x7fffu + ((u >> 16) & 1u);          // round-to-nearest-even
  return (unsigned short)(u >> 16);
}
__device__ __forceinline__ float sigm(float x) {
  float e = __builtin_amdgcn_exp2f(-1.44269504f * x);
  return __builtin_amdgcn_rcpf(1.0f + e);
}
__device__ __forceinline__ float tanh_(float x) {
  float e = __builtin_amdgcn_exp2f(2.88539008f * x);
  return 1.0f - 2.0f * __builtin_amdgcn_rcpf(e + 1.0f);
}

// ---- agent-coherent (sc0 sc1: L1/L2 bypass, L3 coherence point) ops ----
__device__ __forceinline__ unsigned ld_flag(const unsigned* p) {
  unsigned v;
  asm volatile("global_load_dword %0, %1, off sc0 sc1\n\ts_waitcnt vmcnt(0)"
               : "=v"(v) : "v"(p) : "memory");
  return v;
}
__device__ __forceinline__ short8 ld_h16(const void* p) {
  short8 v;
  asm volatile("global_load_dwordx4 %0, %1, off sc0 sc1" : "=v"(v) : "v"(p) : "memory");
  return v;
}
__device__ __forceinline__ void st_h8(void* p, unsigned long long v) {
  asm volatile("global_store_dwordx2 %0, %1, off sc0 sc1" :: "v"(p), "v"(v) : "memory");
}
__device__ __forceinline__ void st_flag(void* p, unsigned v) {
  asm volatile("global_store_dword %0, %1, off sc0 sc1" :: "v"(p), "v"(v) : "memory");
}

// rowp (0..1599) -> original gate row. Slice s owns units 16s..16s+15 as
// 4 tiles: tile{0,2}=i|f, tile{1,3}=g|o of unit octet (tile>>1).
__device__ __forceinline__ int gate_row(int rowp) {
  int s    = rowp >> 6;
  int r    = rowp & 63;
  int tile = r >> 4;
  int c    = r & 15;
  int gate = (tile & 1) * 2 + (c >> 3);
  int u    = s * 16 + (tile >> 1) * 8 + (c & 7);
  return gate * H1n + u;
}

// ---------------- prep ----------------
__global__ void prep_kernel(const float* __restrict__ Wih, const float* __restrict__ Whh,
                            const float* __restrict__ bih, const float* __restrict__ bhh,
                            const float* __restrict__ Wfc, const float* __restrict__ bfc,
                            const float* __restrict__ Wout,
                            unsigned char* __restrict__ ws)
{
  size_t i = (size_t)blockIdx.x * blockDim.x + threadIdx.x;
  const size_t n1 = (size_t)1600 * 448;   // Wbig        716800
  const size_t n2 = (size_t)208 * KP;     // Wfc          86528
  const size_t n3 = 1600;                 // bsum
  const size_t n4 = 208;                  // bfc
  const size_t n5 = 208;                  // wout
  const size_t n6 = (size_t)2 * Bn * KP;  // hbuf         53248
  const size_t n7 = 3200;                 // mailboxes

  if (i < n1) {
    unsigned short* p = (unsigned short*)(ws + OFF_WBIG);
    int rowp = (int)(i / 448), k = (int)(i % 448);
    int r = gate_row(rowp);
    float v = 0.0f;
    if (k < H1n)            v = Whh[(size_t)r * H1n + k];
    else if (k >= 416) { int j = k - 416; if (j < INn) v = Wih[(size_t)r * INn + j]; }
    p[i] = f2bf(v);
    return;
  }
  i -= n1;
  if (i < n2) {
    unsigned short* p = (unsigned short*)(ws + OFF_WFC);
    int r = (int)(i / KP), k = (int)(i % KP);
    p[i] = (r < 200 && k < H1n) ? f2bf(Wfc[(size_t)r * H1n + k]) : (unsigned short)0;
    return;
  }
  i -= n2;
  if (i < n3) { int r = gate_row((int)i);
    ((float*)(ws + OFF_BSUM))[i] = bih[r] + bhh[r]; return; }
  i -= n3;
  if (i < n4) { ((float*)(ws + OFF_BFC))[i] = (i < 200) ? bfc[i] : 0.0f; return; }
  i -= n4;
  if (i < n5) { ((float*)(ws + OFF_WOUT))[i] = (i < 200) ? Wout[i] : 0.0f; return; }
  i -= n5;
  if (i < n6) { ((unsigned short*)(ws + OFF_HBUF))[i] = 0; return; }
  i -= n6;
  if (i < n7) { ((unsigned*)(ws + OFF_FLAG))[i] = 0u; return; }
}

// ---------------- persistent LSTM ----------------
// 25 blocks x 256 thr. Wave w = batch group g (16 rows); block = slice s
// (16 hidden units, 4 gate tiles). Cross-block traffic via sc0sc1 at the L3
// coherence point. Sync: per-consumer replicated mailbox lines -> private-
// line polling, no read sharing, no RMW, no backoff needed.
__global__ void __launch_bounds__(256, 1)
lstm_persist(const float* __restrict__ word, unsigned char* __restrict__ ws)
{
  const int l  = threadIdx.x & 63;
  const int g  = threadIdx.x >> 6;   // batch group 0..3
  const int s  = blockIdx.x;         // slice 0..24
  const int lg = l >> 4, ln = l & 15;
  const int b0 = g * 16;

  const unsigned short* Wbig = (const unsigned short*)(ws + OFF_WBIG);
  const unsigned short* Wfc2 = (const unsigned short*)(ws + OFF_WFC);
  const float* bsum  = (const float*)(ws + OFF_BSUM);
  const float* bfc2  = (const float*)(ws + OFF_BFC);
  const float* wout2 = (const float*)(ws + OFF_WOUT);
  char* hbase = (char*)(ws + OFF_HBUF);
  float* yPart = (float*)(ws + OFF_YPART);
  unsigned* flags = (unsigned*)(ws + OFF_FLAG);

  // ---- persistent weight fragments: 4 gate tiles x 14 k-chunks ----
  short8 wv[4][14];
#pragma unroll
  for (int tl = 0; tl < 4; ++tl) {
    const int rowp = s * 64 + tl * 16 + ln;
#pragma unroll
    for (int kc = 0; kc < 14; ++kc)
      wv[tl][kc] = *(const short8*)(Wbig + (size_t)rowp * 448 + kc * 32 + lg * 8);
  }
  float bs[4];
#pragma unroll
  for (int tl = 0; tl < 4; ++tl) bs[tl] = bsum[s * 64 + tl * 16 + ln];

  const bool isHead = (s < NHT);
  short8 whv[13];
  float bfcv = 0.f, woutv = 0.f;
  if (isHead) {
    const int r = s * 16 + ln;
#pragma unroll
    for (int kc = 0; kc < 13; ++kc)
      whv[kc] = *(const short8*)(Wfc2 + (size_t)r * KP + kc * 32 + lg * 8);
    bfcv  = bfc2[r];
    woutv = wout2[r];
  }

  __shared__ __align__(8) unsigned short sm[4][16][20];   // [wave][unit][b+pad]
  float c[2][4] = {{0.f,0.f,0.f,0.f},{0.f,0.f,0.f,0.f}};
  short8 ha[13];

  // x fragment for t=0
  short8 xa;
  {
    const float* xrow = word + ((size_t)0 * Bn + b0 + ln) * INn;
#pragma unroll
    for (int j = 0; j < 8; ++j) {
      const int k = lg * 8 + j;
      xa[j] = (short)f2bf((k < INn) ? xrow[k] : 0.0f);
    }
  }

  for (int t = 0; t < Tn; ++t) {
    // ---- wait for h(t-1): poll OUR private mailbox line (25 words) ----
    if (t > 0) {
      const unsigned* mb = flags + ((s * 4 + g) << 5);
      const unsigned tt = (unsigned)t;
      while (true) {
        unsigned fv = 0xFFFFFFFFu;
        if (l < NSL) fv = ld_flag(&mb[l]);
        if (__all(fv >= tt)) break;
      }
    }

    // ---- A fragments: 13 pipelined coherent b128 loads, ONE waitcnt ----
    const char* hsrc = hbase
        + ((size_t)((t & 1) ^ 1) * Bn * KP + (size_t)(b0 + ln) * KP) * 2 + lg * 16;
#pragma unroll
    for (int kc = 0; kc < 13; ++kc)
      ha[kc] = ld_h16(hsrc + kc * 64);
    asm volatile("s_waitcnt vmcnt(0)" ::: "memory");
    __builtin_amdgcn_sched_barrier(0);

    // ---- gates: 4 tiles x 14 MFMA (4 independent acc chains) ----
    f32x4 acc[4];
#pragma unroll
    for (int tl = 0; tl < 4; ++tl) { acc[tl][0]=bs[tl]; acc[tl][1]=bs[tl]; acc[tl][2]=bs[tl]; acc[tl][3]=bs[tl]; }
#pragma unroll
    for (int kc = 0; kc < 13; ++kc) {
#pragma unroll
      for (int tl = 0; tl < 4; ++tl)
        acc[tl] = __builtin_amdgcn_mfma_f32_16x16x32_bf16(ha[kc], wv[tl][kc], acc[tl], 0, 0, 0);
    }
#pragma unroll
    for (int tl = 0; tl < 4; ++tl)
      acc[tl] = __builtin_amdgcn_mfma_f32_16x16x32_bf16(xa, wv[tl][13], acc[tl], 0, 0, 0);

    // ---- cell update per unit-octet j; lanes l and l^8 share a unit ----
    const bool hiHalf = (l & 8) != 0;
#pragma unroll
    for (int j = 0; j < 2; ++j) {
      float hr[4];
#pragma unroll
      for (int v = 0; v < 4; ++v) {
        float o0 = acc[2*j][v], o1 = acc[2*j+1][v];
        float p0 = __shfl_xor(o0, 8);
        float p1 = __shfl_xor(o1, 8);
        float iv = hiHalf ? p0 : o0;
        float fv = hiHalf ? o0 : p0;
        float gv = hiHalf ? p1 : o1;
        float ov = hiHalf ? o1 : p1;
        iv = sigm(iv); fv = sigm(fv); gv = tanh_(gv); ov = sigm(ov);
        float cn = fv * c[j][v] + iv * gv;
        float hn = ov * tanh_(cn);
        c[j][v] = fmaxf(cn, 0.f);
        hr[v]   = fmaxf(hn, 0.f);
      }
      if (!hiHalf) {   // canonical copy: unit j*8+ln, batches lg*4+0..3
        unsigned p01 = (unsigned)f2bf(hr[0]) | ((unsigned)f2bf(hr[1]) << 16);
        unsigned p23 = (unsigned)f2bf(hr[2]) | ((unsigned)f2bf(hr[3]) << 16);
        unsigned* pr = (unsigned*)&sm[g][j * 8 + ln][lg << 2];
        pr[0] = p01;
        pr[1] = p23;
      }
    }

    // ---- publish h(t): full-wave u64 coherent store (16 rows x 32B) ----
    {
      char* hdst = hbase + (size_t)(t & 1) * Bn * KP * 2;
      const int b = l & 15, q = l >> 4;   // q = unit quad 0..3
      unsigned long long hq =  (unsigned long long)sm[g][4 * q + 0][b]
          | ((unsigned long long)sm[g][4 * q + 1][b] << 16)
          | ((unsigned long long)sm[g][4 * q + 2][b] << 32)
          | ((unsigned long long)sm[g][4 * q + 3][b] << 48);
      st_h8(hdst + (size_t)(b0 + b) * KP * 2 + s * 32 + q * 8, hq);
    }
    // ---- release: drain h stores, then scatter counter to 25 mailboxes ----
    asm volatile("s_waitcnt vmcnt(0)" ::: "memory");
    if (l < NSL)
      st_flag(&flags[((l * 4 + g) << 5) + s], (unsigned)(t + 1));

    // ---- x(t+1) prefetch: overlaps head MFMA + next poll ----
    if (t + 1 < Tn) {
      const float* xrow = word + ((size_t)(t + 1) * Bn + b0 + ln) * INn;
#pragma unroll
      for (int j = 0; j < 8; ++j) {
        const int k = lg * 8 + j;
        xa[j] = (short)f2bf((k < INn) ? xrow[k] : 0.0f);
      }
    }

    // ---- head tile s for y(t-1): off critical path ----
    if (isHead && t > 0) {
      f32x4 hy = {0.f, 0.f, 0.f, 0.f};
#pragma unroll
      for (int kc = 0; kc < 13; ++kc)
        hy = __builtin_amdgcn_mfma_f32_16x16x32_bf16(ha[kc], whv[kc], hy, 0, 0, 0);
#pragma unroll
      for (int v = 0; v < 4; ++v) {
        float val = fmaxf(hy[v] + bfcv, 0.f) * woutv;
        val += __shfl_xor(val, 1);
        val += __shfl_xor(val, 2);
        val += __shfl_xor(val, 4);
        val += __shfl_xor(val, 8);
        if (ln == 0)
          yPart[(size_t)s * Tn * Bn + (size_t)(t - 1) * Bn + b0 + (lg << 2) + v] = val;
      }
    }
  }

  // ---- epilogue: y(Tn-1) ----
  if (isHead) {
    const unsigned* mb = flags + ((s * 4 + g) << 5);
    while (true) {
      unsigned fv = 0xFFFFFFFFu;
      if (l < NSL) fv = ld_flag(&mb[l]);
      if (__all(fv >= (unsigned)Tn)) break;
    }
    const char* hsrc = hbase
        + ((size_t)((Tn - 1) & 1) * Bn * KP + (size_t)(b0 + ln) * KP) * 2 + lg * 16;
#pragma unroll
    for (int kc = 0; kc < 13; ++kc)
      ha[kc] = ld_h16(hsrc + kc * 64);
    asm volatile("s_waitcnt vmcnt(0)" ::: "memory");
    __builtin_amdgcn_sched_barrier(0);
    f32x4 hy = {0.f, 0.f, 0.f, 0.f};
#pragma unroll
    for (int kc = 0; kc < 13; ++kc)
      hy = __builtin_amdgcn_mfma_f32_16x16x32_bf16(ha[kc], whv[kc], hy, 0, 0, 0);
#pragma unroll
    for (int v = 0; v < 4; ++v) {
      float val = fmaxf(hy[v] + bfcv, 0.f) * woutv;
      val += __shfl_xor(val, 1);
      val += __shfl_xor(val, 2);
      val += __shfl_xor(val, 4);
      val += __shfl_xor(val, 8);
      if (ln == 0)
        yPart[(size_t)s * Tn * Bn + (size_t)(Tn - 1) * Bn + b0 + (lg << 2) + v] = val;
    }
  }
}

// ---------------- finalize: out = sigmoid(sum of 13 partials + b_out) ----------------
__global__ void finalize_kernel(const float* __restrict__ yPart,
                                const float* __restrict__ b_out,
                                float* __restrict__ out)
{
  int i = blockIdx.x * blockDim.x + threadIdx.x;
  if (i < Tn * Bn) {
    float sum = b_out[0];
#pragma unroll
    for (int p = 0; p < 13; ++p)
      sum += yPart[(size_t)p * Tn * Bn + i];
    out[i] = sigm(sum);
  }
}

extern "C" void kernel_launch(void* const* d_in, const int* in_sizes, int n_in,
                              void* d_out, int out_size, void* d_ws, size_t ws_size,
                              hipStream_t stream)
{
  const float* word  = (const float*)d_in[0];
  const float* W_ih  = (const float*)d_in[1];
  const float* W_hh  = (const float*)d_in[2];
  const float* b_ih  = (const float*)d_in[3];
  const float* b_hh  = (const float*)d_in[4];
  const float* W_fc  = (const float*)d_in[5];
  const float* b_fc  = (const float*)d_in[6];
  const float* W_out = (const float*)d_in[7];
  const float* b_out = (const float*)d_in[8];
  unsigned char* ws  = (unsigned char*)d_ws;

  const long long prep_items = 716800LL + 86528 + 1600 + 208 + 208 + 53248 + 3200;
  prep_kernel<<<(int)((prep_items + 255) / 256), 256, 0, stream>>>(
      W_ih, W_hh, b_ih, b_hh, W_fc, b_fc, W_out, ws);
  lstm_persist<<<NSL, 256, 0, stream>>>(word, ws);
  finalize_kernel<<<(Tn * Bn + 255) / 256, 256, 0, stream>>>(
      (const float*)(ws + OFF_YPART), b_out, (float*)d_out);
}

// Round 6
// 6923.563 us; speedup vs baseline: 1.9524x; 1.1436x over previous
//
#include <hip/hip_runtime.h>

// ---------------- problem constants ----------------
#define Tn   2048
#define Bn   64
#define INn  27
#define H1n  400
#define KP   416          // H1 padded to 13 chunks of 32
#define NSL  50           // producer blocks (slices), 8 units each
#define NHB  13           // head blocks (200 fc rows -> 13 tiles of 16)
#define NCONS 63          // mailbox consumers (50 producers + 13 head)
#define RING 8            // h ring depth (slots)

using short8 = __attribute__((ext_vector_type(8))) short;  // 8 bf16 (4 VGPR)
using f32x4  = __attribute__((ext_vector_type(4))) float;  // MFMA acc

// ---------------- workspace layout (bytes) ----------------
#define OFF_WBIG  0u         // bf16 [1600][448]  [Whh|pad|Wih]       1,433,600
#define OFF_WFC   1433600u   // bf16 [208][416]                         173,056
#define OFF_BSUM  1606656u   // f32  [1600]                               6,400
#define OFF_BFC   1613056u   // f32  [208]                                  832
#define OFF_WOUT  1613888u   // f32  [208]                                  832
#define OFF_HBUF  1614720u   // bf16 [8][64][416] ring of h_r           425,984
#define OFF_FLAG  2040704u   // u32  [63 cons][4 grp][64] mailboxes      64,512
#define OFF_YPART 2105216u   // f32  [13][2048*64] head partials      6,815,744
// total 8,920,960

__device__ __forceinline__ unsigned short f2bf(float f) {
  unsigned u = __builtin_bit_cast(unsigned, f);
  u += 0x7fffu + ((u >> 16) & 1u);          // round-to-nearest-even
  return (unsigned short)(u >> 16);
}
__device__ __forceinline__ float sigm(float x) {
  float e = __builtin_amdgcn_exp2f(-1.44269504f * x);
  return __builtin_amdgcn_rcpf(1.0f + e);
}
__device__ __forceinline__ float tanh_(float x) {
  float e = __builtin_amdgcn_exp2f(2.88539008f * x);
  return 1.0f - 2.0f * __builtin_amdgcn_rcpf(e + 1.0f);
}

// ---- agent-coherent (sc0 sc1: L1/L2 bypass, L3 coherence point) ops ----
__device__ __forceinline__ unsigned ld_flag(const unsigned* p) {
  unsigned v;
  asm volatile("global_load_dword %0, %1, off sc0 sc1\n\ts_waitcnt vmcnt(0)"
               : "=v"(v) : "v"(p) : "memory");
  return v;
}
__device__ __forceinline__ short8 ld_h16(const void* p) {
  short8 v;
  asm volatile("global_load_dwordx4 %0, %1, off sc0 sc1" : "=v"(v) : "v"(p) : "memory");
  return v;
}
__device__ __forceinline__ void st_h8(void* p, unsigned long long v) {
  asm volatile("global_store_dwordx2 %0, %1, off sc0 sc1" :: "v"(p), "v"(v) : "memory");
}
__device__ __forceinline__ void st_flag(void* p, unsigned v) {
  asm volatile("global_store_dword %0, %1, off sc0 sc1" :: "v"(p), "v"(v) : "memory");
}

// MFMA with B operand pinned in AGPRs (weights stay resident for the whole
// kernel; AGPRs have no competing consumer so regalloc keeps them).
__device__ __forceinline__ f32x4 mfma_aw(short8 a, short8 w_agpr, f32x4 acc) {
  asm("v_mfma_f32_16x16x32_bf16 %0, %1, %2, %0"
      : "+v"(acc) : "v"(a), "a"(w_agpr));
  return acc;
}

// rowp (0..1599) -> original gate row. Slice s owns units 8s..8s+7 as
// 2 tiles: tile0 = gates i|f, tile1 = g|o (i/f split at col bit 3).
__device__ __forceinline__ int gate_row(int rowp) {
  int s    = rowp >> 5;
  int r32  = rowp & 31;
  int tile = r32 >> 4;
  int c    = r32 & 15;
  int gate = tile * 2 + (c >> 3);
  int u    = s * 8 + (c & 7);
  return gate * H1n + u;
}

// ---------------- prep ----------------
__global__ void prep_kernel(const float* __restrict__ Wih, const float* __restrict__ Whh,
                            const float* __restrict__ bih, const float* __restrict__ bhh,
                            const float* __restrict__ Wfc, const float* __restrict__ bfc,
                            const float* __restrict__ Wout,
                            unsigned char* __restrict__ ws)
{
  size_t i = (size_t)blockIdx.x * blockDim.x + threadIdx.x;
  const size_t n1 = (size_t)1600 * 448;       // Wbig        716800
  const size_t n2 = (size_t)208 * KP;         // Wfc          86528
  const size_t n3 = 1600;                     // bsum
  const size_t n4 = 208;                      // bfc
  const size_t n5 = 208;                      // wout
  const size_t n6 = (size_t)RING * Bn * KP;   // hbuf ring   212992
  const size_t n7 = (size_t)NCONS * 4 * 64;   // mailboxes    16128

  if (i < n1) {
    unsigned short* p = (unsigned short*)(ws + OFF_WBIG);
    int rowp = (int)(i / 448), k = (int)(i % 448);
    int r = gate_row(rowp);
    float v = 0.0f;
    if (k < H1n)            v = Whh[(size_t)r * H1n + k];
    else if (k >= 416) { int j = k - 416; if (j < INn) v = Wih[(size_t)r * INn + j]; }
    p[i] = f2bf(v);
    return;
  }
  i -= n1;
  if (i < n2) {
    unsigned short* p = (unsigned short*)(ws + OFF_WFC);
    int r = (int)(i / KP), k = (int)(i % KP);
    p[i] = (r < 200 && k < H1n) ? f2bf(Wfc[(size_t)r * H1n + k]) : (unsigned short)0;
    return;
  }
  i -= n2;
  if (i < n3) { int r = gate_row((int)i);
    ((float*)(ws + OFF_BSUM))[i] = bih[r] + bhh[r]; return; }
  i -= n3;
  if (i < n4) { ((float*)(ws + OFF_BFC))[i] = (i < 200) ? bfc[i] : 0.0f; return; }
  i -= n4;
  if (i < n5) { ((float*)(ws + OFF_WOUT))[i] = (i < 200) ? Wout[i] : 0.0f; return; }
  i -= n5;
  if (i < n6) { ((unsigned short*)(ws + OFF_HBUF))[i] = 0; return; }
  i -= n6;
  if (i < n7) { ((unsigned*)(ws + OFF_FLAG))[i] = 0u; return; }
}

// ---------------- persistent LSTM ----------------
// 63 blocks x 256 thr; wave w = batch group g. Blocks 0..49: producers
// (slice s = 8 hidden units, 2 gate tiles, weights pinned in AGPRs).
// Blocks 50..62: head consumers (fc tile p, decoupled, ring cushion 7).
// Cross-block traffic via sc0sc1 at L3; private replicated mailbox lines.
__global__ void __launch_bounds__(256, 1)
lstm_persist(const float* __restrict__ word, unsigned char* __restrict__ ws)
{
  const int l  = threadIdx.x & 63;
  const int g  = threadIdx.x >> 6;   // batch group 0..3
  const int lg = l >> 4, ln = l & 15;
  const int b0 = g * 16;

  const unsigned short* Wbig = (const unsigned short*)(ws + OFF_WBIG);
  const unsigned short* Wfc2 = (const unsigned short*)(ws + OFF_WFC);
  const float* bsum  = (const float*)(ws + OFF_BSUM);
  const float* bfc2  = (const float*)(ws + OFF_BFC);
  const float* wout2 = (const float*)(ws + OFF_WOUT);
  char* hbase = (char*)(ws + OFF_HBUF);
  float* yPart = (float*)(ws + OFF_YPART);
  unsigned* flags = (unsigned*)(ws + OFF_FLAG);

  if (blockIdx.x < NSL) {
    // ================= producer path =================
    const int s = blockIdx.x;

    // gate-weight fragments; MFMA "a" constraint pins them in AGPRs
    short8 wv0[13], wv1[13], wx0, wx1;
#pragma unroll
    for (int kc = 0; kc < 13; ++kc) {
      wv0[kc] = *(const short8*)(Wbig + (size_t)(s * 32 + ln)      * 448 + kc * 32 + lg * 8);
      wv1[kc] = *(const short8*)(Wbig + (size_t)(s * 32 + 16 + ln) * 448 + kc * 32 + lg * 8);
    }
    wx0 = *(const short8*)(Wbig + (size_t)(s * 32 + ln)      * 448 + 13 * 32 + lg * 8);
    wx1 = *(const short8*)(Wbig + (size_t)(s * 32 + 16 + ln) * 448 + 13 * 32 + lg * 8);
    const float bs0 = bsum[s * 32 + ln];
    const float bs1 = bsum[s * 32 + 16 + ln];

    __shared__ __align__(8) unsigned short sm[4][8][20];   // [wave][u][b+pad]
    float c[4] = {0.f, 0.f, 0.f, 0.f};
    short8 ha[13];

    // x fragment for t=0
    short8 xa;
    {
      const float* xrow = word + ((size_t)0 * Bn + b0 + ln) * INn;
#pragma unroll
      for (int j = 0; j < 8; ++j) {
        const int k = lg * 8 + j;
        xa[j] = (short)f2bf((k < INn) ? xrow[k] : 0.0f);
      }
    }

    for (int t = 0; t < Tn; ++t) {
      // ---- wait for h(t-1): poll private mailbox line ----
      if (t > 0) {
        const unsigned* mb = flags + ((s * 4 + g) << 6);
        const unsigned tt = (unsigned)t;
        while (true) {
          unsigned fv = 0xFFFFFFFFu;
          if (l < NSL) fv = ld_flag(&mb[l]);
          if (__all(fv >= tt)) break;
        }
      }

      // ---- A fragments: h_r(t-1) from ring slot (t-1)&7 ----
      const char* hsrc = hbase
          + ((size_t)((t - 1) & (RING - 1)) * Bn * KP + (size_t)(b0 + ln) * KP) * 2 + lg * 16;
#pragma unroll
      for (int kc = 0; kc < 13; ++kc)
        ha[kc] = ld_h16(hsrc + kc * 64);
      asm volatile("s_waitcnt vmcnt(0)" ::: "memory");
      __builtin_amdgcn_sched_barrier(0);

      // ---- gates: 2 tiles x 14 MFMA, weights from AGPRs ----
      f32x4 a0 = {bs0, bs0, bs0, bs0};
      f32x4 a1 = {bs1, bs1, bs1, bs1};
#pragma unroll
      for (int kc = 0; kc < 13; ++kc) {
        a0 = mfma_aw(ha[kc], wv0[kc], a0);
        a1 = mfma_aw(ha[kc], wv1[kc], a1);
      }
      a0 = mfma_aw(xa, wx0, a0);
      a1 = mfma_aw(xa, wx1, a1);

      // ---- cell update; lanes l and l^8 share unit, hold i/f and g/o ----
      float hr[4];
      const bool hiHalf = (l & 8) != 0;
#pragma unroll
      for (int v = 0; v < 4; ++v) {
        float o0 = a0[v], o1 = a1[v];
        float p0 = __shfl_xor(o0, 8);
        float p1 = __shfl_xor(o1, 8);
        float iv = hiHalf ? p0 : o0;
        float fv = hiHalf ? o0 : p0;
        float gv = hiHalf ? p1 : o1;
        float ov = hiHalf ? o1 : p1;
        iv = sigm(iv); fv = sigm(fv); gv = tanh_(gv); ov = sigm(ov);
        float cn = fv * c[v] + iv * gv;
        float hn = ov * tanh_(cn);
        c[v]  = fmaxf(cn, 0.f);
        hr[v] = fmaxf(hn, 0.f);
      }

      // ---- transpose 8u x 16b via wave-local LDS ----
      if (!hiHalf) {
        unsigned p01 = (unsigned)f2bf(hr[0]) | ((unsigned)f2bf(hr[1]) << 16);
        unsigned p23 = (unsigned)f2bf(hr[2]) | ((unsigned)f2bf(hr[3]) << 16);
        unsigned* pr = (unsigned*)&sm[g][ln][lg << 2];
        pr[0] = p01;
        pr[1] = p23;
      }
      // ---- publish h(t) into ring slot t&7 ----
      char* hdst = hbase + (size_t)(t & (RING - 1)) * Bn * KP * 2;
      if (l < 32) {
        const int b = l & 15, q = l >> 4;
        unsigned long long hq =  (unsigned long long)sm[g][4 * q + 0][b]
            | ((unsigned long long)sm[g][4 * q + 1][b] << 16)
            | ((unsigned long long)sm[g][4 * q + 2][b] << 32)
            | ((unsigned long long)sm[g][4 * q + 3][b] << 48);
        st_h8(hdst + (size_t)(b0 + b) * KP * 2 + s * 16 + q * 8, hq);
      }
      // ---- release: drain, then scatter counter to all 63 consumers ----
      asm volatile("s_waitcnt vmcnt(0)" ::: "memory");
      if (l < NCONS)
        st_flag(&flags[((l * 4 + g) << 6) + s], (unsigned)(t + 1));

      // ---- x(t+1) prefetch: overlaps next poll ----
      if (t + 1 < Tn) {
        const float* xrow = word + ((size_t)(t + 1) * Bn + b0 + ln) * INn;
#pragma unroll
        for (int j = 0; j < 8; ++j) {
          const int k = lg * 8 + j;
          xa[j] = (short)f2bf((k < INn) ? xrow[k] : 0.0f);
        }
      }
    }
  } else {
    // ================= head-consumer path =================
    const int p = blockIdx.x - NSL;          // fc tile 0..12
    const int cons = NSL + p;

    short8 whv[13];
    {
      const int r = p * 16 + ln;
#pragma unroll
      for (int kc = 0; kc < 13; ++kc)
        whv[kc] = *(const short8*)(Wfc2 + (size_t)r * KP + kc * 32 + lg * 8);
    }
    const float bfcv  = bfc2[p * 16 + ln];
    const float woutv = wout2[p * 16 + ln];
    short8 ha[13];

    for (int t = 0; t < Tn; ++t) {
      // ---- wait for h(t) ----
      {
        const unsigned* mb = flags + ((cons * 4 + g) << 6);
        const unsigned tt = (unsigned)(t + 1);
        while (true) {
          unsigned fv = 0xFFFFFFFFu;
          if (l < NSL) fv = ld_flag(&mb[l]);
          if (__all(fv >= tt)) break;
        }
      }
      const char* hsrc = hbase
          + ((size_t)(t & (RING - 1)) * Bn * KP + (size_t)(b0 + ln) * KP) * 2 + lg * 16;
#pragma unroll
      for (int kc = 0; kc < 13; ++kc)
        ha[kc] = ld_h16(hsrc + kc * 64);
      asm volatile("s_waitcnt vmcnt(0)" ::: "memory");
      __builtin_amdgcn_sched_barrier(0);

      f32x4 hy = {0.f, 0.f, 0.f, 0.f};
#pragma unroll
      for (int kc = 0; kc < 13; ++kc)
        hy = __builtin_amdgcn_mfma_f32_16x16x32_bf16(ha[kc], whv[kc], hy, 0, 0, 0);
#pragma unroll
      for (int v = 0; v < 4; ++v) {
        float val = fmaxf(hy[v] + bfcv, 0.f) * woutv;
        val += __shfl_xor(val, 1);
        val += __shfl_xor(val, 2);
        val += __shfl_xor(val, 4);
        val += __shfl_xor(val, 8);
        if (ln == 0)
          yPart[(size_t)p * Tn * Bn + (size_t)t * Bn + b0 + (lg << 2) + v] = val;
      }
    }
  }
}

// ---------------- finalize: out = sigmoid(sum of 13 partials + b_out) ----------------
__global__ void finalize_kernel(const float* __restrict__ yPart,
                                const float* __restrict__ b_out,
                                float* __restrict__ out)
{
  int i = blockIdx.x * blockDim.x + threadIdx.x;
  if (i < Tn * Bn) {
    float sum = b_out[0];
#pragma unroll
    for (int p = 0; p < 13; ++p)
      sum += yPart[(size_t)p * Tn * Bn + i];
    out[i] = sigm(sum);
  }
}

extern "C" void kernel_launch(void* const* d_in, const int* in_sizes, int n_in,
                              void* d_out, int out_size, void* d_ws, size_t ws_size,
                              hipStream_t stream)
{
  const float* word  = (const float*)d_in[0];
  const float* W_ih  = (const float*)d_in[1];
  const float* W_hh  = (const float*)d_in[2];
  const float* b_ih  = (const float*)d_in[3];
  const float* b_hh  = (const float*)d_in[4];
  const float* W_fc  = (const float*)d_in[5];
  const float* b_fc  = (const float*)d_in[6];
  const float* W_out = (const float*)d_in[7];
  const float* b_out = (const float*)d_in[8];
  unsigned char* ws  = (unsigned char*)d_ws;

  const long long prep_items = 716800LL + 86528 + 1600 + 208 + 208 + 212992 + 16128;
  prep_kernel<<<(int)((prep_items + 255) / 256), 256, 0, stream>>>(
      W_ih, W_hh, b_ih, b_hh, W_fc, b_fc, W_out, ws);
  lstm_persist<<<NSL + NHB, 256, 0, stream>>>(word, ws);
  finalize_kernel<<<(Tn * Bn + 255) / 256, 256, 0, stream>>>(
      (const float*)(ws + OFF_YPART), b_out, (float*)d_out);
}

// Round 9
// 6422.253 us; speedup vs baseline: 2.1048x; 1.0781x over previous
//
#include <hip/hip_runtime.h>

// ---------------- problem constants ----------------
#define Tn   2048
#define Bn   64
#define INn  27
#define H1n  400
#define KP   416          // padded fc K (13 chunks of 32) — Wfc row stride
#define NSL  50           // producer blocks (slices), 8 units each
#define NHB  13           // head blocks (200 fc rows -> 13 tiles of 16)
#define RING 8            // h ring depth (slots)
// hbuf geometry: [slot][g][s][r:16][u:8] bf16 -> 256 B per (g,s), block-exclusive
#define HB_G    12800u    // 50 slices * 256 B
#define HB_SLOT 51200u    // 4 groups * HB_G

using short8 = __attribute__((ext_vector_type(8))) short;  // 8 bf16 (4 VGPR)
using f32x4  = __attribute__((ext_vector_type(4))) float;  // MFMA acc

// ---------------- workspace layout (bytes) ----------------
#define OFF_WBIG  0u         // bf16 [1600][448]  [Whh|pad|Wih]       1,433,600
#define OFF_WFC   1433600u   // bf16 [208][416]                         173,056
#define OFF_BSUM  1606656u   // f32  [1600]                               6,400
#define OFF_BFC   1613056u   // f32  [208]                                  832
#define OFF_WOUT  1613888u   // f32  [208]                                  832
#define OFF_HBUF  1614720u   // bf16 ring [8][4][50][16][8]             409,600
#define OFF_FLAG  2024320u   // u32  [63 cons][4 grp][64] mailboxes      64,512
#define OFF_YPART 2088832u   // f32  [13][2048*64] head partials      6,815,744
// total 8,904,576

__device__ __forceinline__ unsigned short f2bf(float f) {
  unsigned u = __builtin_bit_cast(unsigned, f);
  u += 0x7fffu + ((u >> 16) & 1u);          // round-to-nearest-even
  return (unsigned short)(u >> 16);
}
__device__ __forceinline__ float sigm(float x) {
  float e = __builtin_amdgcn_exp2f(-1.44269504f * x);
  return __builtin_amdgcn_rcpf(1.0f + e);
}
__device__ __forceinline__ float tanh_(float x) {
  float e = __builtin_amdgcn_exp2f(2.88539008f * x);
  return 1.0f - 2.0f * __builtin_amdgcn_rcpf(e + 1.0f);
}

// ---- agent-coherent (sc0 sc1: L1/L2 bypass, L3 coherence point) ops ----
__device__ __forceinline__ unsigned ld_flag(const unsigned* p) {
  unsigned v;
  asm volatile("global_load_dword %0, %1, off sc0 sc1\n\ts_waitcnt vmcnt(0)"
               : "=v"(v) : "v"(p) : "memory");
  return v;
}
__device__ __forceinline__ short8 ld_h16(const void* p) {
  short8 v;
  asm volatile("global_load_dwordx4 %0, %1, off sc0 sc1" : "=v"(v) : "v"(p) : "memory");
  return v;
}
__device__ __forceinline__ void st_h16(void* p, short8 v) {
  asm volatile("global_store_dwordx4 %0, %1, off sc0 sc1" :: "v"(p), "v"(v) : "memory");
}
__device__ __forceinline__ void st_flag(void* p, unsigned v) {
  asm volatile("global_store_dword %0, %1, off sc0 sc1" :: "v"(p), "v"(v) : "memory");
}

// MFMA with B operand pinned in AGPRs (weights resident; proven R5).
__device__ __forceinline__ f32x4 mfma_aw(short8 a, short8 w_agpr, f32x4 acc) {
  asm("v_mfma_f32_16x16x32_bf16 %0, %1, %2, %0"
      : "+v"(acc) : "v"(a), "a"(w_agpr));
  return acc;
}

// rowp (0..1599) -> original gate row. Slice s owns units 8s..8s+7 as
// 2 tiles: tile0 = gates i|f, tile1 = g|o (i/f split at col bit 3).
__device__ __forceinline__ int gate_row(int rowp) {
  int s    = rowp >> 5;
  int r32  = rowp & 31;
  int tile = r32 >> 4;
  int c    = r32 & 15;
  int gate = tile * 2 + (c >> 3);
  int u    = s * 8 + (c & 7);
  return gate * H1n + u;
}

// ---------------- prep ----------------
__global__ void prep_kernel(const float* __restrict__ Wih, const float* __restrict__ Whh,
                            const float* __restrict__ bih, const float* __restrict__ bhh,
                            const float* __restrict__ Wfc, const float* __restrict__ bfc,
                            const float* __restrict__ Wout,
                            unsigned char* __restrict__ ws)
{
  size_t i = (size_t)blockIdx.x * blockDim.x + threadIdx.x;
  const size_t n1 = (size_t)1600 * 448;   // Wbig       716800
  const size_t n2 = (size_t)208 * KP;     // Wfc          86528
  const size_t n3 = 1600;                 // bsum
  const size_t n4 = 208;                  // bfc
  const size_t n5 = 208;                  // wout
  const size_t n6 = (size_t)RING * HB_SLOT / 2;  // hbuf shorts 204800
  const size_t n7 = 16128;                // flag words

  if (i < n1) {
    unsigned short* p = (unsigned short*)(ws + OFF_WBIG);
    int rowp = (int)(i / 448), k = (int)(i % 448);
    int r = gate_row(rowp);
    float v = 0.0f;
    if (k < H1n)            v = Whh[(size_t)r * H1n + k];
    else if (k >= 416) { int jj = k - 416; if (jj < INn) v = Wih[(size_t)r * INn + jj]; }
    p[i] = f2bf(v);
    return;
  }
  i -= n1;
  if (i < n2) {
    unsigned short* p = (unsigned short*)(ws + OFF_WFC);
    int r = (int)(i / KP), k = (int)(i % KP);
    p[i] = (r < 200 && k < H1n) ? f2bf(Wfc[(size_t)r * H1n + k]) : (unsigned short)0;
    return;
  }
  i -= n2;
  if (i < n3) { int r = gate_row((int)i);
    ((float*)(ws + OFF_BSUM))[i] = bih[r] + bhh[r]; return; }
  i -= n3;
  if (i < n4) { ((float*)(ws + OFF_BFC))[i] = (i < 200) ? bfc[i] : 0.0f; return; }
  i -= n4;
  if (i < n5) { ((float*)(ws + OFF_WOUT))[i] = (i < 200) ? Wout[i] : 0.0f; return; }
  i -= n5;
  if (i < n6) { ((unsigned short*)(ws + OFF_HBUF))[i] = 0; return; }
  i -= n6;
  if (i < n7) { ((unsigned*)(ws + OFF_FLAG))[i] = 0u; return; }
}

// ---------------- persistent LSTM ----------------
// 63 blocks x 256 thr (4 waves = 4 batch groups), EXACT R5 sync topology:
// blocks 0..49 producers (slice s: 8 units, 2 gate tiles, AGPR weights),
// blocks 50..62 head consumers (fc tile p). Changes vs R5:
//  (1) hbuf layout [slot][g][s][r16][u8]: publishes are ONE 256-B exclusive
//      block per wave (no cross-block line sharing -> no L3 RMW).
//  (2) heads release consumed slots (word 50+p); producers gate on >= t-7.
__global__ void __launch_bounds__(256, 1)
lstm_persist(const float* __restrict__ word, unsigned char* __restrict__ ws)
{
  const int l  = threadIdx.x & 63;
  const int g  = threadIdx.x >> 6;   // batch group 0..3
  const int lg = l >> 4, ln = l & 15;
  const int b0 = g * 16;

  const unsigned short* Wbig = (const unsigned short*)(ws + OFF_WBIG);
  const unsigned short* Wfc2 = (const unsigned short*)(ws + OFF_WFC);
  const float* bsum  = (const float*)(ws + OFF_BSUM);
  const float* bfc2  = (const float*)(ws + OFF_BFC);
  const float* wout2 = (const float*)(ws + OFF_WOUT);
  char* hbase = (char*)(ws + OFF_HBUF);
  float* yPart = (float*)(ws + OFF_YPART);
  unsigned* flags = (unsigned*)(ws + OFF_FLAG);

  // per-lane constant part of the fragment address: group + lg slice-sub + row
  const size_t hoff = (size_t)g * HB_G + (size_t)lg * 256 + (size_t)ln * 16;

  __shared__ __align__(16) unsigned short smt2[4][16][8];   // [g][row][unit]

  if (blockIdx.x < NSL) {
    // ================= producer path =================
    const int s = blockIdx.x;
    const unsigned* mb = flags + ((s * 4 + g) << 6);

    // gate-weight fragments; mfma "a" constraint pins them in AGPRs
    short8 wv0[13], wv1[13], wx0, wx1;
#pragma unroll
    for (int kc = 0; kc < 13; ++kc) {
      wv0[kc] = *(const short8*)(Wbig + (size_t)(s * 32 + ln)      * 448 + kc * 32 + lg * 8);
      wv1[kc] = *(const short8*)(Wbig + (size_t)(s * 32 + 16 + ln) * 448 + kc * 32 + lg * 8);
    }
    wx0 = *(const short8*)(Wbig + (size_t)(s * 32 + ln)      * 448 + 13 * 32 + lg * 8);
    wx1 = *(const short8*)(Wbig + (size_t)(s * 32 + 16 + ln) * 448 + 13 * 32 + lg * 8);
    const float bs0 = bsum[s * 32 + ln];
    const float bs1 = bsum[s * 32 + 16 + ln];

    float c[4] = {0.f, 0.f, 0.f, 0.f};
    short8 ha[13];

    // x fragment for t=0
    short8 xa;
    {
      const float* xrow = word + ((size_t)0 * Bn + b0 + ln) * INn;
#pragma unroll
      for (int q = 0; q < 8; ++q) {
        const int k = lg * 8 + q;
        xa[q] = (short)f2bf((k < INn) ? xrow[k] : 0.0f);
      }
    }

    for (int t = 0; t < Tn; ++t) {
      // ---- poll private mailbox: producers >= t, heads consumed >= t-7 ----
      if (t > 0) {
        const unsigned tt = (unsigned)t;
        const unsigned need = (l < NSL) ? tt : ((tt >= 8u) ? (tt - 7u) : 0u);
        while (true) {
          unsigned fv = 0xFFFFFFFFu;
          if (l < 63) fv = ld_flag(&mb[l]);
          if (__all(fv >= need)) break;
        }
      }

      // ---- A fragments: 13 pipelined coherent b128 loads, ONE waitcnt ----
      const char* hsrc = hbase + (size_t)((t + RING - 1) & (RING - 1)) * HB_SLOT + hoff;
#pragma unroll
      for (int kc = 0; kc < 13; ++kc)
        ha[kc] = ld_h16(hsrc + kc * 1024);
      asm volatile("s_waitcnt vmcnt(0)" ::: "memory");
      __builtin_amdgcn_sched_barrier(0);

      // ---- gates: 2 tiles x 14 MFMA, weights from AGPRs ----
      f32x4 a0 = {bs0, bs0, bs0, bs0};
      f32x4 a1 = {bs1, bs1, bs1, bs1};
#pragma unroll
      for (int kc = 0; kc < 13; ++kc) {
        a0 = mfma_aw(ha[kc], wv0[kc], a0);
        a1 = mfma_aw(ha[kc], wv1[kc], a1);
      }
      a0 = mfma_aw(xa, wx0, a0);
      a1 = mfma_aw(xa, wx1, a1);

      // ---- cell update; lanes l and l^8 share unit, hold i/f and g/o ----
      const bool hiHalf = (l & 8) != 0;
      float hr[4];
#pragma unroll
      for (int v = 0; v < 4; ++v) {
        float o0 = a0[v], o1 = a1[v];
        float p0 = __shfl_xor(o0, 8);
        float p1 = __shfl_xor(o1, 8);
        float iv = hiHalf ? p0 : o0;
        float fv = hiHalf ? o0 : p0;
        float gv = hiHalf ? p1 : o1;
        float ov = hiHalf ? o1 : p1;
        iv = sigm(iv); fv = sigm(fv); gv = tanh_(gv); ov = sigm(ov);
        float cn = fv * c[v] + iv * gv;
        float hn = ov * tanh_(cn);
        c[v]  = fmaxf(cn, 0.f);
        hr[v] = fmaxf(hn, 0.f);
      }
      // ---- wave-local transpose into smt2[g][row=batch][unit] ----
      if (!hiHalf) {
#pragma unroll
        for (int v = 0; v < 4; ++v)
          smt2[g][lg * 4 + v][ln] = f2bf(hr[v]);
      }
      asm volatile("s_waitcnt lgkmcnt(0)" ::: "memory");

      // ---- publish h(t): ONE exclusive 256-B block (16 lanes x 16 B) ----
      {
        char* hdst = hbase + (size_t)(t & (RING - 1)) * HB_SLOT
                   + (size_t)g * HB_G + (size_t)s * 256;
        if (l < 16) {
          short8 hv = *(const short8*)(&smt2[g][l][0]);
          st_h16(hdst + l * 16, hv);
        }
      }
      // ---- release: drain (1 store), then scatter counter to 63 lines ----
      asm volatile("s_waitcnt vmcnt(0)" ::: "memory");
      if (l < 63)
        st_flag(&flags[((l * 4 + g) << 6) + s], (unsigned)(t + 1));

      // ---- x(t+1) prefetch: overlaps next poll ----
      if (t + 1 < Tn) {
        const float* xrow = word + ((size_t)(t + 1) * Bn + b0 + ln) * INn;
#pragma unroll
        for (int q = 0; q < 8; ++q) {
          const int k = lg * 8 + q;
          xa[q] = (short)f2bf((k < INn) ? xrow[k] : 0.0f);
        }
      }
    }
  } else {
    // ================= head-consumer path =================
    const int p    = blockIdx.x - NSL;       // fc tile 0..12
    const int cons = blockIdx.x;
    const unsigned* mb = flags + ((cons * 4 + g) << 6);

    short8 whv[13];
    {
      const int r = p * 16 + ln;
#pragma unroll
      for (int kc = 0; kc < 13; ++kc)
        whv[kc] = *(const short8*)(Wfc2 + (size_t)r * KP + kc * 32 + lg * 8);
    }
    const float bfcv  = bfc2[p * 16 + ln];
    const float woutv = wout2[p * 16 + ln];
    short8 ha[13];

    for (int t = 0; t < Tn; ++t) {
      // ---- wait for h(t): all 50 producers >= t+1 ----
      {
        const unsigned tt = (unsigned)(t + 1);
        while (true) {
          unsigned fv = 0xFFFFFFFFu;
          if (l < NSL) fv = ld_flag(&mb[l]);
          if (__all(fv >= tt)) break;
        }
      }
      const char* hsrc = hbase + (size_t)(t & (RING - 1)) * HB_SLOT + hoff;
#pragma unroll
      for (int kc = 0; kc < 13; ++kc)
        ha[kc] = ld_h16(hsrc + kc * 1024);
      asm volatile("s_waitcnt vmcnt(0)" ::: "memory");
      __builtin_amdgcn_sched_barrier(0);

      // ---- slot consumed: release to producers (word 50+p) ----
      if (l < NSL)
        st_flag(&flags[((l * 4 + g) << 6) + NSL + p], (unsigned)(t + 1));

      // ---- fc tile p: 13 MFMA (builtin; VGPR weights fine on 13 blocks) ----
      f32x4 hy = {0.f, 0.f, 0.f, 0.f};
#pragma unroll
      for (int kc = 0; kc < 13; ++kc)
        hy = __builtin_amdgcn_mfma_f32_16x16x32_bf16(ha[kc], whv[kc], hy, 0, 0, 0);
#pragma unroll
      for (int v = 0; v < 4; ++v) {
        float val = fmaxf(hy[v] + bfcv, 0.f) * woutv;
        val += __shfl_xor(val, 1);
        val += __shfl_xor(val, 2);
        val += __shfl_xor(val, 4);
        val += __shfl_xor(val, 8);
        if (ln == 0)
          yPart[(size_t)p * Tn * Bn + (size_t)t * Bn + b0 + (lg << 2) + v] = val;
      }
    }
  }
}

// ---------------- finalize: out = sigmoid(sum of 13 partials + b_out) ----------------
__global__ void finalize_kernel(const float* __restrict__ yPart,
                                const float* __restrict__ b_out,
                                float* __restrict__ out)
{
  int i = blockIdx.x * blockDim.x + threadIdx.x;
  if (i < Tn * Bn) {
    float sum = b_out[0];
#pragma unroll
    for (int p = 0; p < 13; ++p)
      sum += yPart[(size_t)p * Tn * Bn + i];
    out[i] = sigm(sum);
  }
}

extern "C" void kernel_launch(void* const* d_in, const int* in_sizes, int n_in,
                              void* d_out, int out_size, void* d_ws, size_t ws_size,
                              hipStream_t stream)
{
  const float* word  = (const float*)d_in[0];
  const float* W_ih  = (const float*)d_in[1];
  const float* W_hh  = (const float*)d_in[2];
  const float* b_ih  = (const float*)d_in[3];
  const float* b_hh  = (const float*)d_in[4];
  const float* W_fc  = (const float*)d_in[5];
  const float* b_fc  = (const float*)d_in[6];
  const float* W_out = (const float*)d_in[7];
  const float* b_out = (const float*)d_in[8];
  unsigned char* ws  = (unsigned char*)d_ws;

  const long long prep_items = 716800LL + 86528 + 1600 + 208 + 208 + 204800 + 16128;
  prep_kernel<<<(int)((prep_items + 255) / 256), 256, 0, stream>>>(
      W_ih, W_hh, b_ih, b_hh, W_fc, b_fc, W_out, ws);
  lstm_persist<<<NSL + NHB, 256, 0, stream>>>(word, ws);
  finalize_kernel<<<(Tn * Bn + 255) / 256, 256, 0, stream>>>(
      (const float*)(ws + OFF_YPART), b_out, (float*)d_out);
}

// Round 10
// 4652.898 us; speedup vs baseline: 2.9052x; 1.3803x over previous
//
#include <hip/hip_runtime.h>

// ---------------- problem constants ----------------
#define Tn   2048
#define Bn   64
#define INn  27
#define H1n  400
#define KP   416          // padded fc K — Wfc row stride
#define NSL  50           // producer blocks (slices), 8 units each
#define NHB  13           // head blocks (fc tiles of 16 rows)
#define RING 8            // h ring depth; epoch parity = (t>>3)&1
// hbuf: [slot][g][s:52][r:16][u:8] bf16; 256 B per (g,s), wave-exclusive
#define HB_G    13312u    // 52 slice blocks (50 real + 2 pad) * 256 B
#define HB_SLOT 53248u    // 4 groups * HB_G

using short8 = __attribute__((ext_vector_type(8))) short;   // 8 bf16
using f32x4  = __attribute__((ext_vector_type(4))) float;   // MFMA acc
using uint4v = __attribute__((ext_vector_type(4))) unsigned;

// ---------------- workspace layout (bytes) ----------------
#define OFF_WBIG  0u         // bf16 [1600][448]  [Whh|pad|Wih]       1,433,600
#define OFF_WFC   1433600u   // bf16 [208][416]                         173,056
#define OFF_BSUM  1606656u   // f32  [1600]                               6,400
#define OFF_BFC   1613056u   // f32  [208]                                  832
#define OFF_WOUT  1613888u   // f32  [208]                                  832
#define OFF_HBUF  1614720u   // bf16 ring [8][4][52][16][8]             425,984
#define OFF_PROG  2040704u   // u32  [4][64] head progress                1,024
#define OFF_YPART 2041728u   // f32  [13][2048*64] head partials      6,815,744
// total 8,857,472

__device__ __forceinline__ unsigned short f2bf(float f) {
  unsigned u = __builtin_bit_cast(unsigned, f);
  u += 0x7fffu + ((u >> 16) & 1u);          // round-to-nearest-even
  return (unsigned short)(u >> 16);
}
__device__ __forceinline__ float sigm(float x) {
  float e = __builtin_amdgcn_exp2f(-1.44269504f * x);
  return __builtin_amdgcn_rcpf(1.0f + e);
}
__device__ __forceinline__ float tanh_(float x) {
  float e = __builtin_amdgcn_exp2f(2.88539008f * x);
  return 1.0f - 2.0f * __builtin_amdgcn_rcpf(e + 1.0f);
}

// ---- agent-coherent (sc0 sc1: L1/L2 bypass, L3 coherence point) ops ----
__device__ __forceinline__ unsigned ld_u32_wait(const unsigned* p) {
  unsigned v;
  asm volatile("global_load_dword %0, %1, off sc0 sc1\n\ts_waitcnt vmcnt(0)"
               : "=v"(v) : "v"(p) : "memory");
  return v;
}
__device__ __forceinline__ unsigned ld_u32_nw(const unsigned* p) {
  unsigned v;
  asm volatile("global_load_dword %0, %1, off sc0 sc1" : "=v"(v) : "v"(p) : "memory");
  return v;
}
__device__ __forceinline__ short8 ld_h16(const void* p) {
  short8 v;
  asm volatile("global_load_dwordx4 %0, %1, off sc0 sc1" : "=v"(v) : "v"(p) : "memory");
  return v;
}
__device__ __forceinline__ void st_h16(void* p, short8 v) {
  asm volatile("global_store_dwordx4 %0, %1, off sc0 sc1" :: "v"(p), "v"(v) : "memory");
}
__device__ __forceinline__ void st_u32(void* p, unsigned v) {
  asm volatile("global_store_dword %0, %1, off sc0 sc1" :: "v"(p), "v"(v) : "memory");
}

// MFMA with B operand pinned in AGPRs (weights resident; proven R5/R8).
__device__ __forceinline__ f32x4 mfma_aw(short8 a, short8 w_agpr, f32x4 acc) {
  asm("v_mfma_f32_16x16x32_bf16 %0, %1, %2, %0"
      : "+v"(acc) : "v"(a), "a"(w_agpr));
  return acc;
}

// rowp (0..1599) -> original gate row. Slice s owns units 8s..8s+7 as
// 2 tiles: tile0 = gates i|f, tile1 = g|o (i/f split at col bit 3).
__device__ __forceinline__ int gate_row(int rowp) {
  int s    = rowp >> 5;
  int r32  = rowp & 31;
  int tile = r32 >> 4;
  int c    = r32 & 15;
  int gate = tile * 2 + (c >> 3);
  int u    = s * 8 + (c & 7);
  return gate * H1n + u;
}

// ---------------- prep ----------------
__global__ void prep_kernel(const float* __restrict__ Wih, const float* __restrict__ Whh,
                            const float* __restrict__ bih, const float* __restrict__ bhh,
                            const float* __restrict__ Wfc, const float* __restrict__ bfc,
                            const float* __restrict__ Wout,
                            unsigned char* __restrict__ ws)
{
  size_t i = (size_t)blockIdx.x * blockDim.x + threadIdx.x;
  const size_t n1 = (size_t)1600 * 448;   // Wbig       716800
  const size_t n2 = (size_t)208 * KP;     // Wfc          86528
  const size_t n3 = 1600;                 // bsum
  const size_t n4 = 208;                  // bfc
  const size_t n5 = 208;                  // wout
  const size_t n6 = (size_t)RING * HB_SLOT / 2;  // hbuf shorts 212992
  const size_t n7 = 256;                  // progress words

  if (i < n1) {
    unsigned short* p = (unsigned short*)(ws + OFF_WBIG);
    int rowp = (int)(i / 448), k = (int)(i % 448);
    int r = gate_row(rowp);
    float v = 0.0f;
    if (k < H1n)            v = Whh[(size_t)r * H1n + k];
    else if (k >= 416) { int jj = k - 416; if (jj < INn) v = Wih[(size_t)r * INn + jj]; }
    p[i] = f2bf(v);
    return;
  }
  i -= n1;
  if (i < n2) {
    unsigned short* p = (unsigned short*)(ws + OFF_WFC);
    int r = (int)(i / KP), k = (int)(i % KP);
    p[i] = (r < 200 && k < H1n) ? f2bf(Wfc[(size_t)r * H1n + k]) : (unsigned short)0;
    return;
  }
  i -= n2;
  if (i < n3) { int r = gate_row((int)i);
    ((float*)(ws + OFF_BSUM))[i] = bih[r] + bhh[r]; return; }
  i -= n3;
  if (i < n4) { ((float*)(ws + OFF_BFC))[i] = (i < 200) ? bfc[i] : 0.0f; return; }
  i -= n4;
  if (i < n5) { ((float*)(ws + OFF_WOUT))[i] = (i < 200) ? Wout[i] : 0.0f; return; }
  i -= n5;
  // hbuf init: 0x8000 (= parity 1) so epoch-0 (parity 0) checks can't
  // false-positive on unwritten data.
  if (i < n6) { ((unsigned short*)(ws + OFF_HBUF))[i] = 0x8000u; return; }
  i -= n6;
  if (i < n7) { ((unsigned*)(ws + OFF_PROG))[i] = 0u; return; }
}

// ---------------- persistent LSTM ----------------
// 63 blocks x 256 thr (wave = batch group). Blocks 0..49: producers (8 units,
// 2 gate tiles, AGPR weights). Blocks 50..62: heads (fc tile p). SYNC: NO
// FLAGS — every stored bf16 carries epoch parity ((t>>3)&1) in its sign bit
// (h_r >= 0 so sign is free). Consumers poll data until all signs match;
// torn reads at any granularity carry stale parity -> detected. Producers
// publish fire-and-forget. Heads report consumed-step in prog[]; producers
// gate publish on head progress >= t-7 (ring-overwrite safety, R6 lesson).
__global__ void __launch_bounds__(256, 1)
lstm_persist(const float* __restrict__ word, unsigned char* __restrict__ ws)
{
  const int l  = threadIdx.x & 63;
  const int g  = threadIdx.x >> 6;   // batch group 0..3
  const int lg = l >> 4, ln = l & 15;
  const int b0 = g * 16;

  const unsigned short* Wbig = (const unsigned short*)(ws + OFF_WBIG);
  const unsigned short* Wfc2 = (const unsigned short*)(ws + OFF_WFC);
  const float* bsum  = (const float*)(ws + OFF_BSUM);
  const float* bfc2  = (const float*)(ws + OFF_BFC);
  const float* wout2 = (const float*)(ws + OFF_WOUT);
  char* hbase = (char*)(ws + OFF_HBUF);
  unsigned* prog = (unsigned*)(ws + OFF_PROG);
  float* yPart = (float*)(ws + OFF_YPART);

  // consumer fragment address: chunk kc covers slices kc*4+lg
  const size_t hoff = (size_t)g * HB_G + (size_t)lg * 256 + (size_t)ln * 16;

  __shared__ __align__(16) unsigned short smt2[4][16][8];   // [g][row][unit]

  if (blockIdx.x < NSL) {
    // ================= producer path =================
    const int s = blockIdx.x;

    short8 wv0[13], wv1[13], wx0, wx1;
#pragma unroll
    for (int kc = 0; kc < 13; ++kc) {
      wv0[kc] = *(const short8*)(Wbig + (size_t)(s * 32 + ln)      * 448 + kc * 32 + lg * 8);
      wv1[kc] = *(const short8*)(Wbig + (size_t)(s * 32 + 16 + ln) * 448 + kc * 32 + lg * 8);
    }
    wx0 = *(const short8*)(Wbig + (size_t)(s * 32 + ln)      * 448 + 13 * 32 + lg * 8);
    wx1 = *(const short8*)(Wbig + (size_t)(s * 32 + 16 + ln) * 448 + 13 * 32 + lg * 8);
    const float bs0 = bsum[s * 32 + ln];
    const float bs1 = bsum[s * 32 + 16 + ln];

    float c[4] = {0.f, 0.f, 0.f, 0.f};
    short8 ha[13];

    short8 xa;
    {
      const float* xrow = word + ((size_t)0 * Bn + b0 + ln) * INn;
#pragma unroll
      for (int q = 0; q < 8; ++q) {
        const int k = lg * 8 + q;
        xa[q] = (short)f2bf((k < INn) ? xrow[k] : 0.0f);
      }
    }

    for (int t = 0; t < Tn; ++t) {
      // ---- head-progress early load (monotonic -> stale-safe) ----
      unsigned hp = 0xFFFFFFFFu;
      if (l < NHB) hp = ld_u32_nw(&prog[g * 64 + l]);

      // ---- poll h(t-1) by parity ----
      if (t > 0) {
        const char* hsrc = hbase + (size_t)((t + RING - 1) & (RING - 1)) * HB_SLOT + hoff;
        const bool expm = (((t - 1) >> 3) & 1) != 0;
        while (true) {
#pragma unroll
          for (int kc = 0; kc < 13; ++kc)
            ha[kc] = ld_h16(hsrc + kc * 1024);
          asm volatile("s_waitcnt vmcnt(0)" ::: "memory");
          __builtin_amdgcn_sched_barrier(0);
          bool ok;
          if (expm) {
            unsigned r = 0xFFFFFFFFu;
#pragma unroll
            for (int kc = 0; kc < 13; ++kc) {
              uint4v u = __builtin_bit_cast(uint4v, ha[kc]);
              unsigned d = u.x & u.y & u.z & u.w;
              if (kc == 12) d = (lg < 2) ? d : 0xFFFFFFFFu;   // mask pad slices
              r &= d;
            }
            ok = ((r & 0x80008000u) == 0x80008000u);
          } else {
            unsigned r = 0u;
#pragma unroll
            for (int kc = 0; kc < 13; ++kc) {
              uint4v u = __builtin_bit_cast(uint4v, ha[kc]);
              unsigned d = u.x | u.y | u.z | u.w;
              if (kc == 12) d = (lg < 2) ? d : 0u;             // mask pad slices
              r |= d;
            }
            ok = ((r & 0x80008000u) == 0u);
          }
          if (__all((int)ok)) break;
        }
        if (expm) {
#pragma unroll
          for (int kc = 0; kc < 13; ++kc) {
            uint4v u = __builtin_bit_cast(uint4v, ha[kc]);
            u.x &= 0x7FFF7FFFu; u.y &= 0x7FFF7FFFu;
            u.z &= 0x7FFF7FFFu; u.w &= 0x7FFF7FFFu;
            ha[kc] = __builtin_bit_cast(short8, u);
          }
        }
        if (lg >= 2) {          // pad-slice garbage: zero (NaN x 0 = NaN!)
          short8 z;
#pragma unroll
          for (int q = 0; q < 8; ++q) z[q] = 0;
          ha[12] = z;
        }
      }

      // ---- gates: 2 tiles x (13 h + 1 x) MFMA, weights from AGPRs ----
      f32x4 a0 = {bs0, bs0, bs0, bs0};
      f32x4 a1 = {bs1, bs1, bs1, bs1};
      if (t > 0) {
#pragma unroll
        for (int kc = 0; kc < 13; ++kc) {
          a0 = mfma_aw(ha[kc], wv0[kc], a0);
          a1 = mfma_aw(ha[kc], wv1[kc], a1);
        }
      }
      a0 = mfma_aw(xa, wx0, a0);
      a1 = mfma_aw(xa, wx1, a1);

      // ---- cell update; lanes l and l^8 share unit, hold i/f and g/o ----
      const bool hiHalf = (l & 8) != 0;
      float hr[4];
#pragma unroll
      for (int v = 0; v < 4; ++v) {
        float o0 = a0[v], o1 = a1[v];
        float p0 = __shfl_xor(o0, 8);
        float p1 = __shfl_xor(o1, 8);
        float iv = hiHalf ? p0 : o0;
        float fv = hiHalf ? o0 : p0;
        float gv = hiHalf ? p1 : o1;
        float ov = hiHalf ? o1 : p1;
        iv = sigm(iv); fv = sigm(fv); gv = tanh_(gv); ov = sigm(ov);
        float cn = fv * c[v] + iv * gv;
        float hn = ov * tanh_(cn);
        c[v]  = fmaxf(cn, 0.f);
        hr[v] = fmaxf(hn, 0.f);
      }
      // ---- wave-local transpose; embed parity of CURRENT step t ----
      const unsigned short pb = (unsigned short)(((t >> 3) & 1) << 15);
      if (!hiHalf) {
#pragma unroll
        for (int v = 0; v < 4; ++v)
          smt2[g][lg * 4 + v][ln] = (unsigned short)(f2bf(hr[v]) | pb);
      }
      asm volatile("s_waitcnt lgkmcnt(0)" ::: "memory");

      // ---- ring-overwrite gate: heads must have consumed step t-7 ----
      if (t >= RING) {
        const unsigned need = (unsigned)(t - (RING - 1));
        bool hok = (l < NHB) ? (hp >= need) : true;
        while (!__all((int)hok)) {
          if (l < NHB) hp = ld_u32_wait(&prog[g * 64 + l]);
          hok = (l < NHB) ? (hp >= need) : true;
        }
      }

      // ---- publish h(t): one exclusive 256-B block, fire-and-forget ----
      {
        char* hdst = hbase + (size_t)(t & (RING - 1)) * HB_SLOT
                   + (size_t)g * HB_G + (size_t)s * 256;
        if (l < 16) {
          short8 hv = *(const short8*)(&smt2[g][l][0]);
          st_h16(hdst + l * 16, hv);
        }
      }

      // ---- x(t+1) prefetch ----
      if (t + 1 < Tn) {
        const float* xrow = word + ((size_t)(t + 1) * Bn + b0 + ln) * INn;
#pragma unroll
        for (int q = 0; q < 8; ++q) {
          const int k = lg * 8 + q;
          xa[q] = (short)f2bf((k < INn) ? xrow[k] : 0.0f);
        }
      }
    }
  } else {
    // ================= head-consumer path =================
    const int p = blockIdx.x - NSL;      // fc tile 0..12

    short8 whv[13];
    {
      const int r = p * 16 + ln;
#pragma unroll
      for (int kc = 0; kc < 13; ++kc)
        whv[kc] = *(const short8*)(Wfc2 + (size_t)r * KP + kc * 32 + lg * 8);
    }
    const float bfcv  = bfc2[p * 16 + ln];
    const float woutv = wout2[p * 16 + ln];
    short8 ha[13];

    for (int t = 0; t < Tn; ++t) {
      // ---- poll h(t) by parity ----
      const char* hsrc = hbase + (size_t)(t & (RING - 1)) * HB_SLOT + hoff;
      const bool expm = (((t >> 3) & 1) != 0);
      while (true) {
#pragma unroll
        for (int kc = 0; kc < 13; ++kc)
          ha[kc] = ld_h16(hsrc + kc * 1024);
        asm volatile("s_waitcnt vmcnt(0)" ::: "memory");
        __builtin_amdgcn_sched_barrier(0);
        bool ok;
        if (expm) {
          unsigned r = 0xFFFFFFFFu;
#pragma unroll
          for (int kc = 0; kc < 13; ++kc) {
            uint4v u = __builtin_bit_cast(uint4v, ha[kc]);
            unsigned d = u.x & u.y & u.z & u.w;
            if (kc == 12) d = (lg < 2) ? d : 0xFFFFFFFFu;
            r &= d;
          }
          ok = ((r & 0x80008000u) == 0x80008000u);
        } else {
          unsigned r = 0u;
#pragma unroll
          for (int kc = 0; kc < 13; ++kc) {
            uint4v u = __builtin_bit_cast(uint4v, ha[kc]);
            unsigned d = u.x | u.y | u.z | u.w;
            if (kc == 12) d = (lg < 2) ? d : 0u;
            r |= d;
          }
          ok = ((r & 0x80008000u) == 0u);
        }
        if (__all((int)ok)) break;
      }
      if (expm) {
#pragma unroll
        for (int kc = 0; kc < 13; ++kc) {
          uint4v u = __builtin_bit_cast(uint4v, ha[kc]);
          u.x &= 0x7FFF7FFFu; u.y &= 0x7FFF7FFFu;
          u.z &= 0x7FFF7FFFu; u.w &= 0x7FFF7FFFu;
          ha[kc] = __builtin_bit_cast(short8, u);
        }
      }
      if (lg >= 2) {
        short8 z;
#pragma unroll
        for (int q = 0; q < 8; ++q) z[q] = 0;
        ha[12] = z;
      }

      // ---- report consumption (data secured in regs) ----
      if (l == 0)
        st_u32(&prog[g * 64 + p], (unsigned)(t + 1));

      // ---- fc tile p + out row ----
      f32x4 hy = {0.f, 0.f, 0.f, 0.f};
#pragma unroll
      for (int kc = 0; kc < 13; ++kc)
        hy = __builtin_amdgcn_mfma_f32_16x16x32_bf16(ha[kc], whv[kc], hy, 0, 0, 0);
#pragma unroll
      for (int v = 0; v < 4; ++v) {
        float val = fmaxf(hy[v] + bfcv, 0.f) * woutv;
        val += __shfl_xor(val, 1);
        val += __shfl_xor(val, 2);
        val += __shfl_xor(val, 4);
        val += __shfl_xor(val, 8);
        if (ln == 0)
          yPart[(size_t)p * Tn * Bn + (size_t)t * Bn + b0 + (lg << 2) + v] = val;
      }
    }
  }
}

// ---------------- finalize: out = sigmoid(sum of 13 partials + b_out) ----------------
__global__ void finalize_kernel(const float* __restrict__ yPart,
                                const float* __restrict__ b_out,
                                float* __restrict__ out)
{
  int i = blockIdx.x * blockDim.x + threadIdx.x;
  if (i < Tn * Bn) {
    float sum = b_out[0];
#pragma unroll
    for (int p = 0; p < 13; ++p)
      sum += yPart[(size_t)p * Tn * Bn + i];
    out[i] = sigm(sum);
  }
}

extern "C" void kernel_launch(void* const* d_in, const int* in_sizes, int n_in,
                              void* d_out, int out_size, void* d_ws, size_t ws_size,
                              hipStream_t stream)
{
  const float* word  = (const float*)d_in[0];
  const float* W_ih  = (const float*)d_in[1];
  const float* W_hh  = (const float*)d_in[2];
  const float* b_ih  = (const float*)d_in[3];
  const float* b_hh  = (const float*)d_in[4];
  const float* W_fc  = (const float*)d_in[5];
  const float* b_fc  = (const float*)d_in[6];
  const float* W_out = (const float*)d_in[7];
  const float* b_out = (const float*)d_in[8];
  unsigned char* ws  = (unsigned char*)d_ws;

  const long long prep_items = 716800LL + 86528 + 1600 + 208 + 208 + 212992 + 256;
  prep_kernel<<<(int)((prep_items + 255) / 256), 256, 0, stream>>>(
      W_ih, W_hh, b_ih, b_hh, W_fc, b_fc, W_out, ws);
  lstm_persist<<<NSL + NHB, 256, 0, stream>>>(word, ws);
  finalize_kernel<<<(Tn * Bn + 255) / 256, 256, 0, stream>>>(
      (const float*)(ws + OFF_YPART), b_out, (float*)d_out);
}